// Round 16
// baseline (410.264 us; speedup 1.0000x reference)
//
#include <hip/hip_runtime.h>
#include <hip/hip_bf16.h>
#include <hip/hip_fp8.h>
#include <math.h>

#define NN 50000
#define EE 800000
#define IN_DIM 128
#define H1 8
#define D1 32
#define HID1 256
#define HID2 128
#define FC1 512
#define NEG_SLOPE 0.2f
#define RANGE 1024

typedef short v8s __attribute__((ext_vector_type(8)));
typedef float v4f __attribute__((ext_vector_type(4)));
typedef float v2f __attribute__((ext_vector_type(2)));
typedef unsigned int v4u __attribute__((ext_vector_type(4)));

__device__ __forceinline__ float bf2f(unsigned short u) {
    unsigned int x = ((unsigned int)u) << 16;
    return __uint_as_float(x);
}
__device__ __forceinline__ unsigned short f2bf(float v) {
    __hip_bfloat16 h = __float2bfloat16(v);
    return *(unsigned short*)&h;
}
__device__ __forceinline__ unsigned char f2f8(float v) {
    __hip_fp8_e4m3 t(v);
    return (unsigned char)t.__x;
}
__device__ __forceinline__ float f8tof(unsigned char u) {
    __hip_fp8_e4m3 t;
    t.__x = (__hip_fp8_storage_t)u;
    return (float)t;
}

__device__ __forceinline__ void f8x4(unsigned int w, float& f0, float& f1, float& f2, float& f3) {
#if __has_builtin(__builtin_amdgcn_cvt_pk_f32_fp8)
    v2f lo = __builtin_amdgcn_cvt_pk_f32_fp8((int)w, false);
    v2f hi = __builtin_amdgcn_cvt_pk_f32_fp8((int)w, true);
    f0 = lo[0]; f1 = lo[1]; f2 = hi[0]; f3 = hi[1];
#else
    f0 = f8tof((unsigned char)(w & 0xff));
    f1 = f8tof((unsigned char)((w >> 8) & 0xff));
    f2 = f8tof((unsigned char)((w >> 16) & 0xff));
    f3 = f8tof((unsigned char)(w >> 24));
#endif
}

// ---------------- CSR build: node-range partitioned, LDS atomics only ----------------

__global__ __launch_bounds__(1024) void hist_ranged_kernel(const int* __restrict__ dst,
                                                           int* __restrict__ counts) {
    __shared__ int hcnt[RANGE];
    int tid = threadIdx.x;
    int base = blockIdx.x * RANGE;
    hcnt[tid] = 0;
    __syncthreads();
    for (int e0 = tid * 4; e0 < EE; e0 += 1024 * 4) {
        int4 d4 = *(const int4*)(dst + e0);
        unsigned int a = (unsigned int)(d4.x - base);
        unsigned int b = (unsigned int)(d4.y - base);
        unsigned int c = (unsigned int)(d4.z - base);
        unsigned int d = (unsigned int)(d4.w - base);
        if (a < RANGE) atomicAdd(&hcnt[a], 1);
        if (b < RANGE) atomicAdd(&hcnt[b], 1);
        if (c < RANGE) atomicAdd(&hcnt[c], 1);
        if (d < RANGE) atomicAdd(&hcnt[d], 1);
    }
    __syncthreads();
    int g = base + tid;
    if (g < NN) counts[g] = hcnt[tid];
}

__global__ __launch_bounds__(256) void scan_a_kernel(const int* __restrict__ counts,
                                                     int* __restrict__ excl,
                                                     int* __restrict__ bsum, int n) {
    __shared__ int wsum[4];
    int tid = threadIdx.x;
    int base = blockIdx.x * 1024 + tid * 4;
    int v0 = 0, v1 = 0, v2 = 0, v3 = 0;
    if (base + 3 < n) {
        int4 t = *(const int4*)(counts + base);
        v0 = t.x; v1 = t.y; v2 = t.z; v3 = t.w;
    } else {
        if (base + 0 < n) v0 = counts[base + 0];
        if (base + 1 < n) v1 = counts[base + 1];
        if (base + 2 < n) v2 = counts[base + 2];
        if (base + 3 < n) v3 = counts[base + 3];
    }
    int tot = v0 + v1 + v2 + v3;
    int lane = tid & 63;
    int w = tid >> 6;
    int x = tot;
    #pragma unroll
    for (int off = 1; off < 64; off <<= 1) {
        int y = __shfl_up(x, off);
        if (lane >= off) x += y;
    }
    if (lane == 63) wsum[w] = x;
    __syncthreads();
    int woff = 0;
    for (int i = 0; i < w; i++) woff += wsum[i];
    int et = woff + x - tot;
    if (base + 0 < n) excl[base + 0] = et;
    if (base + 1 < n) excl[base + 1] = et + v0;
    if (base + 2 < n) excl[base + 2] = et + v0 + v1;
    if (base + 3 < n) excl[base + 3] = et + v0 + v1 + v2;
    if (tid == 255) bsum[blockIdx.x] = woff + x;
}

__global__ __launch_bounds__(64) void scan_b_kernel(int* __restrict__ bsum,
                                                    int* __restrict__ row_ptr, int nb, int n) {
    int lane = threadIdx.x;
    int v = (lane < nb) ? bsum[lane] : 0;
    int x = v;
    #pragma unroll
    for (int off = 1; off < 64; off <<= 1) {
        int y = __shfl_up(x, off);
        if (lane >= off) x += y;
    }
    if (lane < nb) bsum[lane] = x - v;
    if (lane == 63) row_ptr[n] = x;
}

__global__ __launch_bounds__(256) void scan_c_kernel(const int* __restrict__ excl,
                                                     const int* __restrict__ bsum,
                                                     int* __restrict__ row_ptr, int n) {
    int base = blockIdx.x * 1024 + threadIdx.x * 4;
    int off = bsum[blockIdx.x];
    #pragma unroll
    for (int j = 0; j < 4; j++) {
        int i = base + j;
        if (i < n) row_ptr[i] = excl[i] + off;
    }
}

// range-partitioned scatter: block owns nodes [base, base+RANGE); LDS cursors hold
// global positions; pairs stores land in the block's contiguous slice (no XCD ping-pong).
__global__ __launch_bounds__(1024) void scatter_ranged_kernel(const int* __restrict__ src,
                                                              const int* __restrict__ dst,
                                                              const int* __restrict__ row_ptr,
                                                              int2* __restrict__ pairs) {
    __shared__ int cur[RANGE];
    int tid = threadIdx.x;
    int base = blockIdx.x * RANGE;
    int g = base + tid;
    cur[tid] = (g < NN) ? row_ptr[g] : 0;
    __syncthreads();
    for (int e0 = tid * 4; e0 < EE; e0 += 1024 * 4) {
        int4 d4 = *(const int4*)(dst + e0);
        int4 s4 = *(const int4*)(src + e0);
        unsigned int a = (unsigned int)(d4.x - base);
        unsigned int b = (unsigned int)(d4.y - base);
        unsigned int c = (unsigned int)(d4.z - base);
        unsigned int d = (unsigned int)(d4.w - base);
        if (a < RANGE) { int p = atomicAdd(&cur[a], 1); pairs[p] = make_int2(e0 + 0, s4.x); }
        if (b < RANGE) { int p = atomicAdd(&cur[b], 1); pairs[p] = make_int2(e0 + 1, s4.y); }
        if (c < RANGE) { int p = atomicAdd(&cur[c], 1); pairs[p] = make_int2(e0 + 2, s4.z); }
        if (d < RANGE) { int p = atomicAdd(&cur[d], 1); pairs[p] = make_int2(e0 + 3, s4.w); }
    }
}

// ---- fused prep ----

__device__ __forceinline__ void pack_one(const float* __restrict__ B,
                                         __hip_bfloat16* __restrict__ Bp,
                                         int K, int N, int idx) {
    int k = idx / N, n = idx % N;
    int ntile = n >> 4, ks = k >> 5, kk = k & 31;
    int lane = (n & 15) | ((kk >> 3) << 4);
    int j = kk & 7;
    int KS = K >> 5;
    Bp[((size_t)(ntile * KS + ks) * 64 + lane) * 8 + j] = __float2bfloat16(B[idx]);
}

__global__ void prep_kernel(const float* __restrict__ x, __hip_bfloat16* __restrict__ xbf,
                            const float* __restrict__ W1, __hip_bfloat16* __restrict__ W1p,
                            const float* __restrict__ W2, __hip_bfloat16* __restrict__ W2p,
                            const float* __restrict__ fcW1, __hip_bfloat16* __restrict__ fW1p) {
    int i = blockIdx.x * blockDim.x + threadIdx.x;
    const int N0 = NN * IN_DIM;
    const int N1 = N0 + IN_DIM * HID1;
    const int N2 = N1 + HID1 * HID2;
    const int N3 = N2 + HID2 * FC1;
    if (i < N0) xbf[i] = __float2bfloat16(x[i]);
    else if (i < N1) pack_one(W1, W1p, IN_DIM, HID1, i - N0);
    else if (i < N2) pack_one(W2, W2p, HID1, HID2, i - N1);
    else if (i < N3) pack_one(fcW1, fW1p, HID2, FC1, i - N2);
}

// ---------------- MFMA GEMM (bf16 in, fp8 out) + fused attention logits ----------------

template <int ATT>
__global__ __launch_bounds__(256) void mgemm_kernel(const __hip_bfloat16* __restrict__ A,
                                                    const __hip_bfloat16* __restrict__ Bp,
                                                    unsigned char* __restrict__ Cf8,
                                                    const float* __restrict__ as_w,
                                                    const float* __restrict__ ad_w,
                                                    float* __restrict__ a_s,
                                                    float* __restrict__ a_d,
                                                    int M, int K, int N) {
    int w = threadIdx.x >> 6, l = threadIdx.x & 63;
    int bm = blockIdx.x * 128 + w * 32;
    int bn = blockIdx.y * 64;
    int lr = l & 15, lk = l >> 4;
    int KS = K >> 5;
    const short* Ab = (const short*)A;
    const short* Bb = (const short*)Bp;
    v4f acc[2][4];
    #pragma unroll
    for (int mi = 0; mi < 2; mi++)
        #pragma unroll
        for (int nt = 0; nt < 4; nt++) acc[mi][nt] = (v4f)(0.f);
    for (int ks = 0; ks < KS; ks++) {
        v8s a[2];
        #pragma unroll
        for (int mi = 0; mi < 2; mi++) {
            int gm = bm + mi * 16 + lr;
            a[mi] = (gm < M) ? *(const v8s*)(Ab + (size_t)gm * K + ks * 32 + lk * 8)
                             : (v8s)(short)0;
        }
        #pragma unroll
        for (int nt = 0; nt < 4; nt++) {
            int ntile = (bn >> 4) + nt;
            v8s b = *(const v8s*)(Bb + ((size_t)(ntile * KS + ks) * 64 + l) * 8);
            acc[0][nt] = __builtin_amdgcn_mfma_f32_16x16x32_bf16(a[0], b, acc[0][nt], 0, 0, 0);
            acc[1][nt] = __builtin_amdgcn_mfma_f32_16x16x32_bf16(a[1], b, acc[1][nt], 0, 0, 0);
        }
    }
    #pragma unroll
    for (int mi = 0; mi < 2; mi++) {
        #pragma unroll
        for (int nt = 0; nt < 4; nt++) {
            int gn = bn + nt * 16 + lr;
            #pragma unroll
            for (int j = 0; j < 4; j++) {
                int gm = bm + mi * 16 + lk * 4 + j;
                if (gm < M)
                    Cf8[(size_t)gm * N + gn] = f2f8(acc[mi][nt][j]);
            }
        }
    }
    float ws0 = as_w[bn + lr], ws1 = as_w[bn + 16 + lr];
    float ws2 = as_w[bn + 32 + lr], ws3 = as_w[bn + 48 + lr];
    float wd0 = ad_w[bn + lr], wd1 = ad_w[bn + 16 + lr];
    float wd2 = ad_w[bn + 32 + lr], wd3 = ad_w[bn + 48 + lr];
    float sA[2][4], dA[2][4], sB[2][4], dB[2][4];
    #pragma unroll
    for (int mi = 0; mi < 2; mi++)
        #pragma unroll
        for (int j = 0; j < 4; j++) {
            if constexpr (ATT == 1) {
                sA[mi][j] = acc[mi][0][j] * ws0 + acc[mi][1][j] * ws1;
                sB[mi][j] = acc[mi][2][j] * ws2 + acc[mi][3][j] * ws3;
                dA[mi][j] = acc[mi][0][j] * wd0 + acc[mi][1][j] * wd1;
                dB[mi][j] = acc[mi][2][j] * wd2 + acc[mi][3][j] * wd3;
            } else {
                sA[mi][j] = acc[mi][0][j] * ws0 + acc[mi][1][j] * ws1
                          + acc[mi][2][j] * ws2 + acc[mi][3][j] * ws3;
                dA[mi][j] = acc[mi][0][j] * wd0 + acc[mi][1][j] * wd1
                          + acc[mi][2][j] * wd2 + acc[mi][3][j] * wd3;
                sB[mi][j] = 0.f; dB[mi][j] = 0.f;
            }
        }
    #pragma unroll
    for (int off = 1; off < 16; off <<= 1) {
        #pragma unroll
        for (int mi = 0; mi < 2; mi++)
            #pragma unroll
            for (int j = 0; j < 4; j++) {
                sA[mi][j] += __shfl_xor(sA[mi][j], off);
                dA[mi][j] += __shfl_xor(dA[mi][j], off);
                if constexpr (ATT == 1) {
                    sB[mi][j] += __shfl_xor(sB[mi][j], off);
                    dB[mi][j] += __shfl_xor(dB[mi][j], off);
                }
            }
    }
    if (lr == 0) {
        #pragma unroll
        for (int mi = 0; mi < 2; mi++)
            #pragma unroll
            for (int j = 0; j < 4; j++) {
                int row = bm + mi * 16 + lk * 4 + j;
                if (row < M) {
                    if constexpr (ATT == 1) {
                        int h0 = bn >> 5;
                        a_s[(size_t)row * 8 + h0]     = sA[mi][j];
                        a_s[(size_t)row * 8 + h0 + 1] = sB[mi][j];
                        a_d[(size_t)row * 8 + h0]     = dA[mi][j];
                        a_d[(size_t)row * 8 + h0 + 1] = dB[mi][j];
                    } else {
                        atomicAdd(&a_s[row], sA[mi][j]);
                        atomicAdd(&a_d[row], dA[mi][j]);
                    }
                }
            }
    }
}

// ---------------- fused FC head via MFMA ----------------

__global__ __launch_bounds__(256) void fc_mfma_kernel(const __hip_bfloat16* __restrict__ A,
                                                      const __hip_bfloat16* __restrict__ Bp,
                                                      const float* __restrict__ fcb1,
                                                      const float* __restrict__ fcW2,
                                                      const float* __restrict__ fcb2,
                                                      float* __restrict__ out) {
    __shared__ float red[4][32];
    int w = threadIdx.x >> 6, l = threadIdx.x & 63;
    int bm = blockIdx.x * 32;
    int lr = l & 15, lk = l >> 4;
    const int K = HID2, KS = K >> 5;
    const short* Ab = (const short*)A;
    const short* Bb = (const short*)Bp;
    v4f acc[2][8];
    #pragma unroll
    for (int mi = 0; mi < 2; mi++)
        #pragma unroll
        for (int nt = 0; nt < 8; nt++) acc[mi][nt] = (v4f)(0.f);
    for (int ks = 0; ks < KS; ks++) {
        v8s a[2];
        #pragma unroll
        for (int mi = 0; mi < 2; mi++) {
            int gm = bm + mi * 16 + lr;
            a[mi] = (gm < NN) ? *(const v8s*)(Ab + (size_t)gm * K + ks * 32 + lk * 8)
                              : (v8s)(short)0;
        }
        #pragma unroll
        for (int nt = 0; nt < 8; nt++) {
            int ntile = w * 8 + nt;
            v8s b = *(const v8s*)(Bb + ((size_t)(ntile * KS + ks) * 64 + l) * 8);
            acc[0][nt] = __builtin_amdgcn_mfma_f32_16x16x32_bf16(a[0], b, acc[0][nt], 0, 0, 0);
            acc[1][nt] = __builtin_amdgcn_mfma_f32_16x16x32_bf16(a[1], b, acc[1][nt], 0, 0, 0);
        }
    }
    float p[2][4];
    #pragma unroll
    for (int mi = 0; mi < 2; mi++)
        #pragma unroll
        for (int j = 0; j < 4; j++) p[mi][j] = 0.f;
    #pragma unroll
    for (int nt = 0; nt < 8; nt++) {
        int col = w * 128 + nt * 16 + lr;
        float b1v = fcb1[col], w2v = fcW2[col];
        #pragma unroll
        for (int mi = 0; mi < 2; mi++) {
            #pragma unroll
            for (int j = 0; j < 4; j++) {
                float v = acc[mi][nt][j] + b1v;
                p[mi][j] += ((v > 0.f) ? v : 0.f) * w2v;
            }
        }
    }
    #pragma unroll
    for (int mi = 0; mi < 2; mi++)
        #pragma unroll
        for (int j = 0; j < 4; j++) {
            float v = p[mi][j];
            v += __shfl_xor(v, 1);
            v += __shfl_xor(v, 2);
            v += __shfl_xor(v, 4);
            v += __shfl_xor(v, 8);
            p[mi][j] = v;
        }
    if (lr == 0) {
        #pragma unroll
        for (int mi = 0; mi < 2; mi++)
            #pragma unroll
            for (int j = 0; j < 4; j++) red[w][mi * 16 + lk * 4 + j] = p[mi][j];
    }
    __syncthreads();
    int tid = threadIdx.x;
    if (tid < 32) {
        int gm = bm + tid;
        if (gm < NN)
            out[gm] = red[0][tid] + red[1][tid] + red[2][tid] + red[3][tid] + fcb2[0];
    }
}

// ---------------- fused layer-1 softmax + aggregation ----------------

template <int KM>
__device__ __forceinline__ void gat1_fast(int lane, int start, int cnt,
                                          const int2* __restrict__ pairs,
                                          const float* __restrict__ a_s, float ad,
                                          const unsigned char* __restrict__ hf8,
                                          float* __restrict__ alpha1_out,
                                          float& acc0, float& acc1, float& acc2, float& acc3) {
    int h = lane & 7, j = lane >> 3;
    int hl = lane >> 3;
    int cl = min(lane, cnt - 1);
    int2 ep = pairs[start + cl];
    int e_all = ep.x, s_all = ep.y;
    unsigned int loff = (unsigned int)(lane << 2);

    if constexpr (KM <= 4) {
        constexpr int NB = KM * 8;
        int sj[KM];
        float ev[KM];
        #pragma unroll
        for (int k = 0; k < KM; k++) {
            int idx = j + k * 8;
            sj[k] = __shfl(s_all, idx);
            ev[k] = a_s[(size_t)sj[k] * 8 + h];
        }
        unsigned int qt[NB];
        #pragma unroll
        for (int e = 0; e < NB; e++) {
            int sje = __shfl(s_all, e);
            qt[e] = *(const unsigned int*)(hf8 + (((unsigned int)sje << 8) | loff));
        }
        float ex[KM];
        #pragma unroll
        for (int k = 0; k < KM; k++) {
            int idx = j + k * 8;
            float v = ev[k] + ad;
            v = (v >= 0.f) ? v : NEG_SLOPE * v;
            ex[k] = (idx < cnt) ? v : -INFINITY;
        }
        float m = ex[0];
        #pragma unroll
        for (int k = 1; k < KM; k++) m = fmaxf(m, ex[k]);
        m = fmaxf(m, __shfl_xor(m, 8));
        m = fmaxf(m, __shfl_xor(m, 16));
        m = fmaxf(m, __shfl_xor(m, 32));
        float s = 0.f;
        #pragma unroll
        for (int k = 0; k < KM; k++) {
            ex[k] = expf(ex[k] - m);
            s += ex[k];
        }
        s += __shfl_xor(s, 8);
        s += __shfl_xor(s, 16);
        s += __shfl_xor(s, 32);
        float inv = 1.f / (s + 1e-16f);
        #pragma unroll
        for (int k = 0; k < KM; k++) ex[k] *= inv;
        #pragma unroll
        for (int k = 0; k < KM; k++) {
            int idx = j + k * 8;
            int eo = __shfl(e_all, idx);
            if (idx < cnt) alpha1_out[(size_t)eo * 8 + h] = ex[k];
        }
        #pragma unroll
        for (int e = 0; e < NB; e++) {
            float At = __shfl(ex[e >> 3], (e & 7) * 8 + hl);
            float f0, f1, f2, f3;
            f8x4(qt[e], f0, f1, f2, f3);
            acc0 += At * f0;
            acc1 += At * f1;
            acc2 += At * f2;
            acc3 += At * f3;
        }
    } else {
        float ex[KM];
        int sj[KM];
        #pragma unroll
        for (int k = 0; k < KM; k++) {
            int idx = j + k * 8;
            sj[k] = __shfl(s_all, idx);
            float v = a_s[(size_t)sj[k] * 8 + h] + ad;
            v = (v >= 0.f) ? v : NEG_SLOPE * v;
            ex[k] = (idx < cnt) ? v : -INFINITY;
        }
        float m = ex[0];
        #pragma unroll
        for (int k = 1; k < KM; k++) m = fmaxf(m, ex[k]);
        m = fmaxf(m, __shfl_xor(m, 8));
        m = fmaxf(m, __shfl_xor(m, 16));
        m = fmaxf(m, __shfl_xor(m, 32));
        float s = 0.f;
        #pragma unroll
        for (int k = 0; k < KM; k++) {
            ex[k] = expf(ex[k] - m);
            s += ex[k];
        }
        s += __shfl_xor(s, 8);
        s += __shfl_xor(s, 16);
        s += __shfl_xor(s, 32);
        float inv = 1.f / (s + 1e-16f);
        #pragma unroll
        for (int k = 0; k < KM; k++) ex[k] *= inv;
        #pragma unroll
        for (int k = 0; k < KM; k++) {
            int idx = j + k * 8;
            int eo = __shfl(e_all, idx);
            if (idx < cnt) alpha1_out[(size_t)eo * 8 + h] = ex[k];
        }
        unsigned int pk[KM];
        #pragma unroll
        for (int k = 0; k < KM; k++)
            pk[k] = ((unsigned int)sj[k] << 16) | (unsigned int)f2bf(ex[k]);
        int rounds = (cnt + 7) >> 3;
        #pragma unroll
        for (int K = 0; K < KM; K++) {
            if (K < rounds) {
                float At[8];
                unsigned int qt[8];
                #pragma unroll
                for (int t = 0; t < 8; t++) {
                    unsigned int wv = (unsigned int)__shfl((int)pk[K], t * 8 + hl);
                    At[t] = bf2f((unsigned short)wv);
                    qt[t] = *(const unsigned int*)(hf8 + (((wv >> 16) << 8) | loff));
                }
                #pragma unroll
                for (int t = 0; t < 8; t++) {
                    float f0, f1, f2, f3;
                    f8x4(qt[t], f0, f1, f2, f3);
                    acc0 += At[t] * f0;
                    acc1 += At[t] * f1;
                    acc2 += At[t] * f2;
                    acc3 += At[t] * f3;
                }
            }
        }
    }
}

__global__ __launch_bounds__(256) void gat1_kernel(const int* __restrict__ row_ptr,
                                                   const int2* __restrict__ pairs,
                                                   const float* __restrict__ a_s,
                                                   const float* __restrict__ a_d,
                                                   const unsigned char* __restrict__ h1f8,
                                                   const float* __restrict__ b1,
                                                   float* __restrict__ alpha1_out,
                                                   __hip_bfloat16* __restrict__ x1bf) {
    int wv = threadIdx.x >> 6, lane = threadIdx.x & 63;
    int n = blockIdx.x * 4 + wv;
    if (n >= NN) return;
    int start = row_ptr[n], end = row_ptr[n + 1];
    int cnt = end - start;
    int h = lane & 7, j = lane >> 3;
    int hl = lane >> 3;
    unsigned int loff = (unsigned int)(lane << 2);
    float acc0 = 0.f, acc1 = 0.f, acc2 = 0.f, acc3 = 0.f;
    if (cnt > 0 && cnt <= 64) {
        float ad = a_d[(size_t)n * 8 + h];
        if (cnt <= 8)
            gat1_fast<1>(lane, start, cnt, pairs, a_s, ad, h1f8, alpha1_out, acc0, acc1, acc2, acc3);
        else if (cnt <= 16)
            gat1_fast<2>(lane, start, cnt, pairs, a_s, ad, h1f8, alpha1_out, acc0, acc1, acc2, acc3);
        else if (cnt <= 24)
            gat1_fast<3>(lane, start, cnt, pairs, a_s, ad, h1f8, alpha1_out, acc0, acc1, acc2, acc3);
        else if (cnt <= 32)
            gat1_fast<4>(lane, start, cnt, pairs, a_s, ad, h1f8, alpha1_out, acc0, acc1, acc2, acc3);
        else
            gat1_fast<8>(lane, start, cnt, pairs, a_s, ad, h1f8, alpha1_out, acc0, acc1, acc2, acc3);
    } else if (cnt > 64) {
        float ad = a_d[(size_t)n * 8 + h];
        float m = -INFINITY;
        for (int p = start + j; p < end; p += 8) {
            float v = a_s[(size_t)pairs[p].y * 8 + h] + ad;
            v = (v >= 0.f) ? v : NEG_SLOPE * v;
            m = fmaxf(m, v);
        }
        m = fmaxf(m, __shfl_xor(m, 8));
        m = fmaxf(m, __shfl_xor(m, 16));
        m = fmaxf(m, __shfl_xor(m, 32));
        float s = 0.f;
        for (int p = start + j; p < end; p += 8) {
            float v = a_s[(size_t)pairs[p].y * 8 + h] + ad;
            v = (v >= 0.f) ? v : NEG_SLOPE * v;
            s += expf(v - m);
        }
        s += __shfl_xor(s, 8);
        s += __shfl_xor(s, 16);
        s += __shfl_xor(s, 32);
        float inv = 1.f / (s + 1e-16f);
        for (int p = start + j; p < end; p += 8) {
            int2 ep = pairs[p];
            float v = a_s[(size_t)ep.y * 8 + h] + ad;
            v = (v >= 0.f) ? v : NEG_SLOPE * v;
            alpha1_out[(size_t)ep.x * 8 + h] = expf(v - m) * inv;
        }
        float mh = __shfl(m, hl);
        float invh = __shfl(inv, hl);
        float adh = __shfl(ad, hl);
        for (int p = start; p < end; p++) {
            int sp = pairs[p].y;
            float v = a_s[(size_t)sp * 8 + hl] + adh;
            v = (v >= 0.f) ? v : NEG_SLOPE * v;
            float al = expf(v - mh) * invh;
            unsigned int q = *(const unsigned int*)(h1f8 + (((unsigned int)sp << 8) | loff));
            float f0, f1, f2, f3;
            f8x4(q, f0, f1, f2, f3);
            acc0 += al * f0;
            acc1 += al * f1;
            acc2 += al * f2;
            acc3 += al * f3;
        }
    }
    float4 bb = *(const float4*)(b1 + lane * 4);
    float r0 = acc0 + bb.x, r1 = acc1 + bb.y, r2 = acc2 + bb.z, r3 = acc3 + bb.w;
    r0 = (r0 > 0.f) ? r0 : expf(r0) - 1.f;
    r1 = (r1 > 0.f) ? r1 : expf(r1) - 1.f;
    r2 = (r2 > 0.f) ? r2 : expf(r2) - 1.f;
    r3 = (r3 > 0.f) ? r3 : expf(r3) - 1.f;
    ushort4 o;
    o.x = f2bf(r0); o.y = f2bf(r1); o.z = f2bf(r2); o.w = f2bf(r3);
    *(ushort4*)((unsigned short*)x1bf + (size_t)n * HID1 + lane * 4) = o;
}

// ---------------- fused layer-2 softmax + aggregation ----------------

template <int RM>
__device__ __forceinline__ void gat2_fast(int lane, int start, int cnt, int r, int c,
                                          const int2* __restrict__ pairs,
                                          const float* __restrict__ a_s, float ad,
                                          const unsigned char* __restrict__ hf8,
                                          float* __restrict__ alpha2_out,
                                          float& acc0, float& acc1, float& acc2, float& acc3) {
    bool act = lane < cnt;
    int ii = min(lane, cnt - 1);
    int2 ep = pairs[start + ii];
    int sj = ep.y;
    float asv = a_s[sj];
    unsigned int coff = (unsigned int)(c << 2);
    constexpr int NB = RM * 4;
    unsigned int qt[NB];
    #pragma unroll
    for (int t = 0; t < NB; t++) {
        int je = (t >> 2) * 8 + (t & 3) * 2 + r;
        int sje = __shfl(sj, je);
        qt[t] = *(const unsigned int*)(hf8 + (((unsigned int)sje << 7) | coff));
    }
    float v = asv + ad;
    v = (v >= 0.f) ? v : NEG_SLOPE * v;
    float e = act ? v : -INFINITY;
    float m = e;
    #pragma unroll
    for (int off = 1; off < 64; off <<= 1) m = fmaxf(m, __shfl_xor(m, off));
    float ex = expf(e - m);
    float s = ex;
    #pragma unroll
    for (int off = 1; off < 64; off <<= 1) s += __shfl_xor(s, off);
    float al = ex / (s + 1e-16f);
    if (act) alpha2_out[ep.x] = al;
    #pragma unroll
    for (int t = 0; t < NB; t++) {
        int je = (t >> 2) * 8 + (t & 3) * 2 + r;
        float At = __shfl(al, je);
        float f0, f1, f2, f3;
        f8x4(qt[t], f0, f1, f2, f3);
        acc0 += At * f0;
        acc1 += At * f1;
        acc2 += At * f2;
        acc3 += At * f3;
    }
}

__global__ __launch_bounds__(256) void gat2_kernel(const int* __restrict__ row_ptr,
                                                   const int2* __restrict__ pairs,
                                                   const float* __restrict__ a_s,
                                                   const float* __restrict__ a_d,
                                                   const unsigned char* __restrict__ h2f8,
                                                   const float* __restrict__ b2,
                                                   float* __restrict__ alpha2_out,
                                                   __hip_bfloat16* __restrict__ x2bf) {
    int wv = threadIdx.x >> 6, lane = threadIdx.x & 63;
    int n = blockIdx.x * 4 + wv;
    if (n >= NN) return;
    int start = row_ptr[n], end = row_ptr[n + 1];
    int cnt = end - start;
    int r = lane >> 5, c = lane & 31;
    float acc0 = 0.f, acc1 = 0.f, acc2 = 0.f, acc3 = 0.f;
    if (cnt > 0 && cnt <= 64) {
        float ad = a_d[n];
        if (cnt <= 8)
            gat2_fast<1>(lane, start, cnt, r, c, pairs, a_s, ad, h2f8, alpha2_out, acc0, acc1, acc2, acc3);
        else if (cnt <= 16)
            gat2_fast<2>(lane, start, cnt, r, c, pairs, a_s, ad, h2f8, alpha2_out, acc0, acc1, acc2, acc3);
        else if (cnt <= 32)
            gat2_fast<4>(lane, start, cnt, r, c, pairs, a_s, ad, h2f8, alpha2_out, acc0, acc1, acc2, acc3);
        else
            gat2_fast<8>(lane, start, cnt, r, c, pairs, a_s, ad, h2f8, alpha2_out, acc0, acc1, acc2, acc3);
    } else if (cnt > 64) {
        float ad = a_d[n];
        unsigned int coff = (unsigned int)(c << 2);
        float m = -INFINITY;
        for (int p = start + lane; p < end; p += 64) {
            float v = a_s[pairs[p].y] + ad;
            v = (v >= 0.f) ? v : NEG_SLOPE * v;
            m = fmaxf(m, v);
        }
        for (int off = 32; off; off >>= 1) m = fmaxf(m, __shfl_xor(m, off));
        float s = 0.f;
        for (int p = start + lane; p < end; p += 64) {
            float v = a_s[pairs[p].y] + ad;
            v = (v >= 0.f) ? v : NEG_SLOPE * v;
            s += expf(v - m);
        }
        for (int off = 32; off; off >>= 1) s += __shfl_xor(s, off);
        float inv = 1.f / (s + 1e-16f);
        for (int p = start + lane; p < end; p += 64) {
            int2 ep = pairs[p];
            float v = a_s[ep.y] + ad;
            v = (v >= 0.f) ? v : NEG_SLOPE * v;
            alpha2_out[ep.x] = expf(v - m) * inv;
        }
        for (int p = start + r; p < end; p += 2) {
            int sp = pairs[p].y;
            float v = a_s[sp] + ad;
            v = (v >= 0.f) ? v : NEG_SLOPE * v;
            float al = expf(v - m) * inv;
            unsigned int q = *(const unsigned int*)(h2f8 + (((unsigned int)sp << 7) | coff));
            float f0, f1, f2, f3;
            f8x4(q, f0, f1, f2, f3);
            acc0 += al * f0;
            acc1 += al * f1;
            acc2 += al * f2;
            acc3 += al * f3;
        }
    }
    acc0 += __shfl_xor(acc0, 32);
    acc1 += __shfl_xor(acc1, 32);
    acc2 += __shfl_xor(acc2, 32);
    acc3 += __shfl_xor(acc3, 32);
    if (r == 0) {
        float4 bb = *(const float4*)(b2 + c * 4);
        float r0 = acc0 + bb.x, r1 = acc1 + bb.y, r2 = acc2 + bb.z, r3 = acc3 + bb.w;
        r0 = (r0 > 0.f) ? r0 : 0.f;
        r1 = (r1 > 0.f) ? r1 : 0.f;
        r2 = (r2 > 0.f) ? r2 : 0.f;
        r3 = (r3 > 0.f) ? r3 : 0.f;
        ushort4 o;
        o.x = f2bf(r0); o.y = f2bf(r1); o.z = f2bf(r2); o.w = f2bf(r3);
        *(ushort4*)((unsigned short*)x2bf + (size_t)n * HID2 + c * 4) = o;
    }
}

// ---------------- host launch ----------------

extern "C" void kernel_launch(void* const* d_in, const int* in_sizes, int n_in,
                              void* d_out, int out_size, void* d_ws, size_t ws_size,
                              hipStream_t stream) {
    (void)in_sizes; (void)n_in; (void)out_size; (void)ws_size;
    const float* x        = (const float*)d_in[0];
    const int*   eindex   = (const int*)d_in[1];
    const float* W1       = (const float*)d_in[2];
    const float* att_src1 = (const float*)d_in[3];
    const float* att_dst1 = (const float*)d_in[4];
    const float* b1       = (const float*)d_in[5];
    const float* W2       = (const float*)d_in[6];
    const float* att_src2 = (const float*)d_in[7];
    const float* att_dst2 = (const float*)d_in[8];
    const float* b2       = (const float*)d_in[9];
    const float* fcW1     = (const float*)d_in[10];
    const float* fcb1     = (const float*)d_in[11];
    const float* fcW2     = (const float*)d_in[12];
    const float* fcb2     = (const float*)d_in[13];

    const int* src = eindex;
    const int* dst = eindex + EE;

    float* out_n      = (float*)d_out;               // [N]
    float* alpha1_out = out_n + NN;                  // [E,8]
    float* alpha2_out = alpha1_out + (size_t)EE * 8; // [E]

    char* ws = (char*)d_ws;
    size_t off = 0;
    auto alloc = [&](size_t bytes) {
        size_t o = off;
        off = (off + bytes + 255) & ~(size_t)255;
        return o;
    };
    size_t o_rowptr = alloc((NN + 1) * sizeof(int));
    size_t o_ctot   = alloc(NN * sizeof(int));
    size_t o_excl   = alloc(NN * sizeof(int));
    size_t o_bsum   = alloc(64 * sizeof(int));
    size_t o_pairs  = alloc((size_t)EE * sizeof(int2));
    size_t o_as1    = alloc((size_t)NN * H1 * sizeof(float));
    size_t o_ad1    = alloc((size_t)NN * H1 * sizeof(float));
    size_t o_as2    = alloc((size_t)NN * sizeof(float));
    size_t o_ad2    = alloc((size_t)NN * sizeof(float));
    size_t o_h1f8   = alloc((size_t)NN * HID1);
    size_t o_xbf    = alloc((size_t)NN * IN_DIM * sizeof(__hip_bfloat16));
    size_t o_x1bf   = alloc((size_t)NN * HID1 * sizeof(__hip_bfloat16));
    size_t o_h2f8   = alloc((size_t)NN * HID2);
    size_t o_x2bf   = alloc((size_t)NN * HID2 * sizeof(__hip_bfloat16));
    size_t o_W1p    = alloc((size_t)IN_DIM * HID1 * sizeof(__hip_bfloat16));
    size_t o_W2p    = alloc((size_t)HID1 * HID2 * sizeof(__hip_bfloat16));
    size_t o_fW1p   = alloc((size_t)HID2 * FC1 * sizeof(__hip_bfloat16));

    int*   row_ptr    = (int*)(ws + o_rowptr);
    int*   counts_tot = (int*)(ws + o_ctot);
    int*   excl       = (int*)(ws + o_excl);
    int*   bsum       = (int*)(ws + o_bsum);
    int2*  pairs      = (int2*)(ws + o_pairs);
    float* a_s1       = (float*)(ws + o_as1);
    float* a_d1       = (float*)(ws + o_ad1);
    float* a_s2       = (float*)(ws + o_as2);
    float* a_d2       = (float*)(ws + o_ad2);
    unsigned char*  h1f8  = (unsigned char*)(ws + o_h1f8);
    __hip_bfloat16* xbf   = (__hip_bfloat16*)(ws + o_xbf);
    __hip_bfloat16* x1bf  = (__hip_bfloat16*)(ws + o_x1bf);
    unsigned char*  h2f8  = (unsigned char*)(ws + o_h2f8);
    __hip_bfloat16* x2bf  = (__hip_bfloat16*)(ws + o_x2bf);
    __hip_bfloat16* W1p   = (__hip_bfloat16*)(ws + o_W1p);
    __hip_bfloat16* W2p   = (__hip_bfloat16*)(ws + o_W2p);
    __hip_bfloat16* fW1p  = (__hip_bfloat16*)(ws + o_fW1p);

    const int SCAN_NB = (NN + 1023) / 1024;  // 49
    const int NRANGE = (NN + RANGE - 1) / RANGE;  // 49
    const int PREP_N = NN * IN_DIM + IN_DIM * HID1 + HID1 * HID2 + HID2 * FC1;

    hipMemsetAsync(a_s2, 0, NN * sizeof(float), stream);
    hipMemsetAsync(a_d2, 0, NN * sizeof(float), stream);

    // ---- CSR build: LDS-atomic ranged histogram + scatter (no global atomics) ----
    hist_ranged_kernel<<<NRANGE, 1024, 0, stream>>>(dst, counts_tot);
    scan_a_kernel<<<SCAN_NB, 256, 0, stream>>>(counts_tot, excl, bsum, NN);
    scan_b_kernel<<<1, 64, 0, stream>>>(bsum, row_ptr, SCAN_NB, NN);
    scan_c_kernel<<<SCAN_NB, 256, 0, stream>>>(excl, bsum, row_ptr, NN);
    scatter_ranged_kernel<<<NRANGE, 1024, 0, stream>>>(src, dst, row_ptr, pairs);

    prep_kernel<<<(PREP_N + 255) / 256, 256, 0, stream>>>(x, xbf, W1, W1p, W2, W2p, fcW1, fW1p);

    mgemm_kernel<1><<<dim3((NN + 127) / 128, HID1 / 64), 256, 0, stream>>>(
        xbf, W1p, h1f8, att_src1, att_dst1, a_s1, a_d1, NN, IN_DIM, HID1);
    gat1_kernel<<<(NN + 3) / 4, 256, 0, stream>>>(row_ptr, pairs, a_s1, a_d1,
                                                  h1f8, b1, alpha1_out, x1bf);

    mgemm_kernel<2><<<dim3((NN + 127) / 128, HID2 / 64), 256, 0, stream>>>(
        x1bf, W2p, h2f8, att_src2, att_dst2, a_s2, a_d2, NN, HID1, HID2);
    gat2_kernel<<<(NN + 3) / 4, 256, 0, stream>>>(row_ptr, pairs, a_s2, a_d2,
                                                  h2f8, b2, alpha2_out, x2bf);

    fc_mfma_kernel<<<(NN + 31) / 32, 256, 0, stream>>>(x2bf, fW1p, fcb1, fcW2, fcb2, out_n);
}

// Round 17
// 224.183 us; speedup vs baseline: 1.8300x; 1.8300x over previous
//
#include <hip/hip_runtime.h>
#include <hip/hip_bf16.h>
#include <hip/hip_fp8.h>
#include <math.h>

#define NN 50000
#define EE 800000
#define IN_DIM 128
#define H1 8
#define D1 32
#define HID1 256
#define HID2 128
#define FC1 512
#define NEG_SLOPE 0.2f
#define RANGE 1024
#define NCH 16
#define CHSZ (EE / NCH)

typedef short v8s __attribute__((ext_vector_type(8)));
typedef float v4f __attribute__((ext_vector_type(4)));
typedef float v2f __attribute__((ext_vector_type(2)));
typedef unsigned int v4u __attribute__((ext_vector_type(4)));

__device__ __forceinline__ float bf2f(unsigned short u) {
    unsigned int x = ((unsigned int)u) << 16;
    return __uint_as_float(x);
}
__device__ __forceinline__ unsigned short f2bf(float v) {
    __hip_bfloat16 h = __float2bfloat16(v);
    return *(unsigned short*)&h;
}
__device__ __forceinline__ unsigned char f2f8(float v) {
    __hip_fp8_e4m3 t(v);
    return (unsigned char)t.__x;
}
__device__ __forceinline__ float f8tof(unsigned char u) {
    __hip_fp8_e4m3 t;
    t.__x = (__hip_fp8_storage_t)u;
    return (float)t;
}

__device__ __forceinline__ void f8x4(unsigned int w, float& f0, float& f1, float& f2, float& f3) {
#if __has_builtin(__builtin_amdgcn_cvt_pk_f32_fp8)
    v2f lo = __builtin_amdgcn_cvt_pk_f32_fp8((int)w, false);
    v2f hi = __builtin_amdgcn_cvt_pk_f32_fp8((int)w, true);
    f0 = lo[0]; f1 = lo[1]; f2 = hi[0]; f3 = hi[1];
#else
    f0 = f8tof((unsigned char)(w & 0xff));
    f1 = f8tof((unsigned char)((w >> 8) & 0xff));
    f2 = f8tof((unsigned char)((w >> 16) & 0xff));
    f3 = f8tof((unsigned char)(w >> 24));
#endif
}

// ---------------- CSR build: 2D (node-range x edge-chunk), LDS atomics only ----------

__global__ __launch_bounds__(1024) void hist2d_kernel(const int* __restrict__ dst,
                                                      int* __restrict__ counts_part) {
    __shared__ int hcnt[RANGE];
    int tid = threadIdx.x;
    int base = blockIdx.x * RANGE;
    int cy = blockIdx.y;
    hcnt[tid] = 0;
    __syncthreads();
    int e_begin = cy * CHSZ;
    int e_end = e_begin + CHSZ;
    for (int e0 = e_begin + tid * 4; e0 < e_end; e0 += 1024 * 4) {
        int4 d4 = *(const int4*)(dst + e0);
        unsigned int a = (unsigned int)(d4.x - base);
        unsigned int b = (unsigned int)(d4.y - base);
        unsigned int c = (unsigned int)(d4.z - base);
        unsigned int d = (unsigned int)(d4.w - base);
        if (a < RANGE) atomicAdd(&hcnt[a], 1);
        if (b < RANGE) atomicAdd(&hcnt[b], 1);
        if (c < RANGE) atomicAdd(&hcnt[c], 1);
        if (d < RANGE) atomicAdd(&hcnt[d], 1);
    }
    __syncthreads();
    int g = base + tid;
    if (g < NN) counts_part[cy * NN + g] = hcnt[tid];
}

__global__ void reduce_kernel(const int* __restrict__ counts_part, int* __restrict__ counts_total) {
    int d = blockIdx.x * blockDim.x + threadIdx.x;
    if (d >= NN) return;
    int t = 0;
    #pragma unroll
    for (int c = 0; c < NCH; c++) t += counts_part[c * NN + d];
    counts_total[d] = t;
}

__global__ __launch_bounds__(256) void scan_a_kernel(const int* __restrict__ counts,
                                                     int* __restrict__ excl,
                                                     int* __restrict__ bsum, int n) {
    __shared__ int wsum[4];
    int tid = threadIdx.x;
    int base = blockIdx.x * 1024 + tid * 4;
    int v0 = 0, v1 = 0, v2 = 0, v3 = 0;
    if (base + 3 < n) {
        int4 t = *(const int4*)(counts + base);
        v0 = t.x; v1 = t.y; v2 = t.z; v3 = t.w;
    } else {
        if (base + 0 < n) v0 = counts[base + 0];
        if (base + 1 < n) v1 = counts[base + 1];
        if (base + 2 < n) v2 = counts[base + 2];
        if (base + 3 < n) v3 = counts[base + 3];
    }
    int tot = v0 + v1 + v2 + v3;
    int lane = tid & 63;
    int w = tid >> 6;
    int x = tot;
    #pragma unroll
    for (int off = 1; off < 64; off <<= 1) {
        int y = __shfl_up(x, off);
        if (lane >= off) x += y;
    }
    if (lane == 63) wsum[w] = x;
    __syncthreads();
    int woff = 0;
    for (int i = 0; i < w; i++) woff += wsum[i];
    int et = woff + x - tot;
    if (base + 0 < n) excl[base + 0] = et;
    if (base + 1 < n) excl[base + 1] = et + v0;
    if (base + 2 < n) excl[base + 2] = et + v0 + v1;
    if (base + 3 < n) excl[base + 3] = et + v0 + v1 + v2;
    if (tid == 255) bsum[blockIdx.x] = woff + x;
}

__global__ __launch_bounds__(64) void scan_b_kernel(int* __restrict__ bsum,
                                                    int* __restrict__ row_ptr, int nb, int n) {
    int lane = threadIdx.x;
    int v = (lane < nb) ? bsum[lane] : 0;
    int x = v;
    #pragma unroll
    for (int off = 1; off < 64; off <<= 1) {
        int y = __shfl_up(x, off);
        if (lane >= off) x += y;
    }
    if (lane < nb) bsum[lane] = x - v;
    if (lane == 63) row_ptr[n] = x;
}

__global__ __launch_bounds__(256) void scan_c_kernel(const int* __restrict__ excl,
                                                     const int* __restrict__ bsum,
                                                     int* __restrict__ row_ptr, int n) {
    int base = blockIdx.x * 1024 + threadIdx.x * 4;
    int off = bsum[blockIdx.x];
    #pragma unroll
    for (int j = 0; j < 4; j++) {
        int i = base + j;
        if (i < n) row_ptr[i] = excl[i] + off;
    }
}

// cursor_part[c][d] = row_ptr[d] + sum_{c'<c} counts_part[c'][d]
__global__ void base2d_kernel(const int* __restrict__ row_ptr, const int* __restrict__ counts_part,
                              int* __restrict__ cursor_part) {
    int d = blockIdx.x * blockDim.x + threadIdx.x;
    if (d >= NN) return;
    int running = row_ptr[d];
    #pragma unroll
    for (int c = 0; c < NCH; c++) {
        cursor_part[c * NN + d] = running;
        running += counts_part[c * NN + d];
    }
}

__global__ __launch_bounds__(1024) void scatter2d_kernel(const int* __restrict__ src,
                                                         const int* __restrict__ dst,
                                                         const int* __restrict__ cursor_part,
                                                         int2* __restrict__ pairs) {
    __shared__ int cur[RANGE];
    int tid = threadIdx.x;
    int base = blockIdx.x * RANGE;
    int cy = blockIdx.y;
    int g = base + tid;
    cur[tid] = (g < NN) ? cursor_part[cy * NN + g] : 0;
    __syncthreads();
    int e_begin = cy * CHSZ;
    int e_end = e_begin + CHSZ;
    for (int e0 = e_begin + tid * 4; e0 < e_end; e0 += 1024 * 4) {
        int4 d4 = *(const int4*)(dst + e0);
        int4 s4 = *(const int4*)(src + e0);
        unsigned int a = (unsigned int)(d4.x - base);
        unsigned int b = (unsigned int)(d4.y - base);
        unsigned int c = (unsigned int)(d4.z - base);
        unsigned int d = (unsigned int)(d4.w - base);
        if (a < RANGE) { int p = atomicAdd(&cur[a], 1); pairs[p] = make_int2(e0 + 0, s4.x); }
        if (b < RANGE) { int p = atomicAdd(&cur[b], 1); pairs[p] = make_int2(e0 + 1, s4.y); }
        if (c < RANGE) { int p = atomicAdd(&cur[c], 1); pairs[p] = make_int2(e0 + 2, s4.z); }
        if (d < RANGE) { int p = atomicAdd(&cur[d], 1); pairs[p] = make_int2(e0 + 3, s4.w); }
    }
}

// ---- fused prep ----

__device__ __forceinline__ void pack_one(const float* __restrict__ B,
                                         __hip_bfloat16* __restrict__ Bp,
                                         int K, int N, int idx) {
    int k = idx / N, n = idx % N;
    int ntile = n >> 4, ks = k >> 5, kk = k & 31;
    int lane = (n & 15) | ((kk >> 3) << 4);
    int j = kk & 7;
    int KS = K >> 5;
    Bp[((size_t)(ntile * KS + ks) * 64 + lane) * 8 + j] = __float2bfloat16(B[idx]);
}

__global__ void prep_kernel(const float* __restrict__ x, __hip_bfloat16* __restrict__ xbf,
                            const float* __restrict__ W1, __hip_bfloat16* __restrict__ W1p,
                            const float* __restrict__ W2, __hip_bfloat16* __restrict__ W2p,
                            const float* __restrict__ fcW1, __hip_bfloat16* __restrict__ fW1p) {
    int i = blockIdx.x * blockDim.x + threadIdx.x;
    const int N0 = NN * IN_DIM;
    const int N1 = N0 + IN_DIM * HID1;
    const int N2 = N1 + HID1 * HID2;
    const int N3 = N2 + HID2 * FC1;
    if (i < N0) xbf[i] = __float2bfloat16(x[i]);
    else if (i < N1) pack_one(W1, W1p, IN_DIM, HID1, i - N0);
    else if (i < N2) pack_one(W2, W2p, HID1, HID2, i - N1);
    else if (i < N3) pack_one(fcW1, fW1p, HID2, FC1, i - N2);
}

// ---------------- MFMA GEMM (bf16 in, fp8 out) + fused attention logits ----------------

template <int ATT>
__global__ __launch_bounds__(256) void mgemm_kernel(const __hip_bfloat16* __restrict__ A,
                                                    const __hip_bfloat16* __restrict__ Bp,
                                                    unsigned char* __restrict__ Cf8,
                                                    const float* __restrict__ as_w,
                                                    const float* __restrict__ ad_w,
                                                    float* __restrict__ a_s,
                                                    float* __restrict__ a_d,
                                                    int M, int K, int N) {
    int w = threadIdx.x >> 6, l = threadIdx.x & 63;
    int bm = blockIdx.x * 128 + w * 32;
    int bn = blockIdx.y * 64;
    int lr = l & 15, lk = l >> 4;
    int KS = K >> 5;
    const short* Ab = (const short*)A;
    const short* Bb = (const short*)Bp;
    v4f acc[2][4];
    #pragma unroll
    for (int mi = 0; mi < 2; mi++)
        #pragma unroll
        for (int nt = 0; nt < 4; nt++) acc[mi][nt] = (v4f)(0.f);
    for (int ks = 0; ks < KS; ks++) {
        v8s a[2];
        #pragma unroll
        for (int mi = 0; mi < 2; mi++) {
            int gm = bm + mi * 16 + lr;
            a[mi] = (gm < M) ? *(const v8s*)(Ab + (size_t)gm * K + ks * 32 + lk * 8)
                             : (v8s)(short)0;
        }
        #pragma unroll
        for (int nt = 0; nt < 4; nt++) {
            int ntile = (bn >> 4) + nt;
            v8s b = *(const v8s*)(Bb + ((size_t)(ntile * KS + ks) * 64 + l) * 8);
            acc[0][nt] = __builtin_amdgcn_mfma_f32_16x16x32_bf16(a[0], b, acc[0][nt], 0, 0, 0);
            acc[1][nt] = __builtin_amdgcn_mfma_f32_16x16x32_bf16(a[1], b, acc[1][nt], 0, 0, 0);
        }
    }
    #pragma unroll
    for (int mi = 0; mi < 2; mi++) {
        #pragma unroll
        for (int nt = 0; nt < 4; nt++) {
            int gn = bn + nt * 16 + lr;
            #pragma unroll
            for (int j = 0; j < 4; j++) {
                int gm = bm + mi * 16 + lk * 4 + j;
                if (gm < M)
                    Cf8[(size_t)gm * N + gn] = f2f8(acc[mi][nt][j]);
            }
        }
    }
    float ws0 = as_w[bn + lr], ws1 = as_w[bn + 16 + lr];
    float ws2 = as_w[bn + 32 + lr], ws3 = as_w[bn + 48 + lr];
    float wd0 = ad_w[bn + lr], wd1 = ad_w[bn + 16 + lr];
    float wd2 = ad_w[bn + 32 + lr], wd3 = ad_w[bn + 48 + lr];
    float sA[2][4], dA[2][4], sB[2][4], dB[2][4];
    #pragma unroll
    for (int mi = 0; mi < 2; mi++)
        #pragma unroll
        for (int j = 0; j < 4; j++) {
            if constexpr (ATT == 1) {
                sA[mi][j] = acc[mi][0][j] * ws0 + acc[mi][1][j] * ws1;
                sB[mi][j] = acc[mi][2][j] * ws2 + acc[mi][3][j] * ws3;
                dA[mi][j] = acc[mi][0][j] * wd0 + acc[mi][1][j] * wd1;
                dB[mi][j] = acc[mi][2][j] * wd2 + acc[mi][3][j] * wd3;
            } else {
                sA[mi][j] = acc[mi][0][j] * ws0 + acc[mi][1][j] * ws1
                          + acc[mi][2][j] * ws2 + acc[mi][3][j] * ws3;
                dA[mi][j] = acc[mi][0][j] * wd0 + acc[mi][1][j] * wd1
                          + acc[mi][2][j] * wd2 + acc[mi][3][j] * wd3;
                sB[mi][j] = 0.f; dB[mi][j] = 0.f;
            }
        }
    #pragma unroll
    for (int off = 1; off < 16; off <<= 1) {
        #pragma unroll
        for (int mi = 0; mi < 2; mi++)
            #pragma unroll
            for (int j = 0; j < 4; j++) {
                sA[mi][j] += __shfl_xor(sA[mi][j], off);
                dA[mi][j] += __shfl_xor(dA[mi][j], off);
                if constexpr (ATT == 1) {
                    sB[mi][j] += __shfl_xor(sB[mi][j], off);
                    dB[mi][j] += __shfl_xor(dB[mi][j], off);
                }
            }
    }
    if (lr == 0) {
        #pragma unroll
        for (int mi = 0; mi < 2; mi++)
            #pragma unroll
            for (int j = 0; j < 4; j++) {
                int row = bm + mi * 16 + lk * 4 + j;
                if (row < M) {
                    if constexpr (ATT == 1) {
                        int h0 = bn >> 5;
                        a_s[(size_t)row * 8 + h0]     = sA[mi][j];
                        a_s[(size_t)row * 8 + h0 + 1] = sB[mi][j];
                        a_d[(size_t)row * 8 + h0]     = dA[mi][j];
                        a_d[(size_t)row * 8 + h0 + 1] = dB[mi][j];
                    } else {
                        atomicAdd(&a_s[row], sA[mi][j]);
                        atomicAdd(&a_d[row], dA[mi][j]);
                    }
                }
            }
    }
}

// ---------------- fused FC head via MFMA ----------------

__global__ __launch_bounds__(256) void fc_mfma_kernel(const __hip_bfloat16* __restrict__ A,
                                                      const __hip_bfloat16* __restrict__ Bp,
                                                      const float* __restrict__ fcb1,
                                                      const float* __restrict__ fcW2,
                                                      const float* __restrict__ fcb2,
                                                      float* __restrict__ out) {
    __shared__ float red[4][32];
    int w = threadIdx.x >> 6, l = threadIdx.x & 63;
    int bm = blockIdx.x * 32;
    int lr = l & 15, lk = l >> 4;
    const int K = HID2, KS = K >> 5;
    const short* Ab = (const short*)A;
    const short* Bb = (const short*)Bp;
    v4f acc[2][8];
    #pragma unroll
    for (int mi = 0; mi < 2; mi++)
        #pragma unroll
        for (int nt = 0; nt < 8; nt++) acc[mi][nt] = (v4f)(0.f);
    for (int ks = 0; ks < KS; ks++) {
        v8s a[2];
        #pragma unroll
        for (int mi = 0; mi < 2; mi++) {
            int gm = bm + mi * 16 + lr;
            a[mi] = (gm < NN) ? *(const v8s*)(Ab + (size_t)gm * K + ks * 32 + lk * 8)
                              : (v8s)(short)0;
        }
        #pragma unroll
        for (int nt = 0; nt < 8; nt++) {
            int ntile = w * 8 + nt;
            v8s b = *(const v8s*)(Bb + ((size_t)(ntile * KS + ks) * 64 + l) * 8);
            acc[0][nt] = __builtin_amdgcn_mfma_f32_16x16x32_bf16(a[0], b, acc[0][nt], 0, 0, 0);
            acc[1][nt] = __builtin_amdgcn_mfma_f32_16x16x32_bf16(a[1], b, acc[1][nt], 0, 0, 0);
        }
    }
    float p[2][4];
    #pragma unroll
    for (int mi = 0; mi < 2; mi++)
        #pragma unroll
        for (int j = 0; j < 4; j++) p[mi][j] = 0.f;
    #pragma unroll
    for (int nt = 0; nt < 8; nt++) {
        int col = w * 128 + nt * 16 + lr;
        float b1v = fcb1[col], w2v = fcW2[col];
        #pragma unroll
        for (int mi = 0; mi < 2; mi++) {
            #pragma unroll
            for (int j = 0; j < 4; j++) {
                float v = acc[mi][nt][j] + b1v;
                p[mi][j] += ((v > 0.f) ? v : 0.f) * w2v;
            }
        }
    }
    #pragma unroll
    for (int mi = 0; mi < 2; mi++)
        #pragma unroll
        for (int j = 0; j < 4; j++) {
            float v = p[mi][j];
            v += __shfl_xor(v, 1);
            v += __shfl_xor(v, 2);
            v += __shfl_xor(v, 4);
            v += __shfl_xor(v, 8);
            p[mi][j] = v;
        }
    if (lr == 0) {
        #pragma unroll
        for (int mi = 0; mi < 2; mi++)
            #pragma unroll
            for (int j = 0; j < 4; j++) red[w][mi * 16 + lk * 4 + j] = p[mi][j];
    }
    __syncthreads();
    int tid = threadIdx.x;
    if (tid < 32) {
        int gm = bm + tid;
        if (gm < NN)
            out[gm] = red[0][tid] + red[1][tid] + red[2][tid] + red[3][tid] + fcb2[0];
    }
}

// ---------------- fused layer-1 softmax + aggregation ----------------

template <int KM>
__device__ __forceinline__ void gat1_fast(int lane, int start, int cnt,
                                          const int2* __restrict__ pairs,
                                          const float* __restrict__ a_s, float ad,
                                          const unsigned char* __restrict__ hf8,
                                          float* __restrict__ alpha1_out,
                                          float& acc0, float& acc1, float& acc2, float& acc3) {
    int h = lane & 7, j = lane >> 3;
    int hl = lane >> 3;
    int cl = min(lane, cnt - 1);
    int2 ep = pairs[start + cl];
    int e_all = ep.x, s_all = ep.y;
    unsigned int loff = (unsigned int)(lane << 2);

    if constexpr (KM <= 4) {
        constexpr int NB = KM * 8;
        int sj[KM];
        float ev[KM];
        #pragma unroll
        for (int k = 0; k < KM; k++) {
            int idx = j + k * 8;
            sj[k] = __shfl(s_all, idx);
            ev[k] = a_s[(size_t)sj[k] * 8 + h];
        }
        unsigned int qt[NB];
        #pragma unroll
        for (int e = 0; e < NB; e++) {
            int sje = __shfl(s_all, e);
            qt[e] = *(const unsigned int*)(hf8 + (((unsigned int)sje << 8) | loff));
        }
        float ex[KM];
        #pragma unroll
        for (int k = 0; k < KM; k++) {
            int idx = j + k * 8;
            float v = ev[k] + ad;
            v = (v >= 0.f) ? v : NEG_SLOPE * v;
            ex[k] = (idx < cnt) ? v : -INFINITY;
        }
        float m = ex[0];
        #pragma unroll
        for (int k = 1; k < KM; k++) m = fmaxf(m, ex[k]);
        m = fmaxf(m, __shfl_xor(m, 8));
        m = fmaxf(m, __shfl_xor(m, 16));
        m = fmaxf(m, __shfl_xor(m, 32));
        float s = 0.f;
        #pragma unroll
        for (int k = 0; k < KM; k++) {
            ex[k] = expf(ex[k] - m);
            s += ex[k];
        }
        s += __shfl_xor(s, 8);
        s += __shfl_xor(s, 16);
        s += __shfl_xor(s, 32);
        float inv = 1.f / (s + 1e-16f);
        #pragma unroll
        for (int k = 0; k < KM; k++) ex[k] *= inv;
        #pragma unroll
        for (int k = 0; k < KM; k++) {
            int idx = j + k * 8;
            int eo = __shfl(e_all, idx);
            if (idx < cnt) alpha1_out[(size_t)eo * 8 + h] = ex[k];
        }
        #pragma unroll
        for (int e = 0; e < NB; e++) {
            float At = __shfl(ex[e >> 3], (e & 7) * 8 + hl);
            float f0, f1, f2, f3;
            f8x4(qt[e], f0, f1, f2, f3);
            acc0 += At * f0;
            acc1 += At * f1;
            acc2 += At * f2;
            acc3 += At * f3;
        }
    } else {
        float ex[KM];
        int sj[KM];
        #pragma unroll
        for (int k = 0; k < KM; k++) {
            int idx = j + k * 8;
            sj[k] = __shfl(s_all, idx);
            float v = a_s[(size_t)sj[k] * 8 + h] + ad;
            v = (v >= 0.f) ? v : NEG_SLOPE * v;
            ex[k] = (idx < cnt) ? v : -INFINITY;
        }
        float m = ex[0];
        #pragma unroll
        for (int k = 1; k < KM; k++) m = fmaxf(m, ex[k]);
        m = fmaxf(m, __shfl_xor(m, 8));
        m = fmaxf(m, __shfl_xor(m, 16));
        m = fmaxf(m, __shfl_xor(m, 32));
        float s = 0.f;
        #pragma unroll
        for (int k = 0; k < KM; k++) {
            ex[k] = expf(ex[k] - m);
            s += ex[k];
        }
        s += __shfl_xor(s, 8);
        s += __shfl_xor(s, 16);
        s += __shfl_xor(s, 32);
        float inv = 1.f / (s + 1e-16f);
        #pragma unroll
        for (int k = 0; k < KM; k++) ex[k] *= inv;
        #pragma unroll
        for (int k = 0; k < KM; k++) {
            int idx = j + k * 8;
            int eo = __shfl(e_all, idx);
            if (idx < cnt) alpha1_out[(size_t)eo * 8 + h] = ex[k];
        }
        unsigned int pk[KM];
        #pragma unroll
        for (int k = 0; k < KM; k++)
            pk[k] = ((unsigned int)sj[k] << 16) | (unsigned int)f2bf(ex[k]);
        int rounds = (cnt + 7) >> 3;
        #pragma unroll
        for (int K = 0; K < KM; K++) {
            if (K < rounds) {
                float At[8];
                unsigned int qt[8];
                #pragma unroll
                for (int t = 0; t < 8; t++) {
                    unsigned int wv = (unsigned int)__shfl((int)pk[K], t * 8 + hl);
                    At[t] = bf2f((unsigned short)wv);
                    qt[t] = *(const unsigned int*)(hf8 + (((wv >> 16) << 8) | loff));
                }
                #pragma unroll
                for (int t = 0; t < 8; t++) {
                    float f0, f1, f2, f3;
                    f8x4(qt[t], f0, f1, f2, f3);
                    acc0 += At[t] * f0;
                    acc1 += At[t] * f1;
                    acc2 += At[t] * f2;
                    acc3 += At[t] * f3;
                }
            }
        }
    }
}

__global__ __launch_bounds__(256) void gat1_kernel(const int* __restrict__ row_ptr,
                                                   const int2* __restrict__ pairs,
                                                   const float* __restrict__ a_s,
                                                   const float* __restrict__ a_d,
                                                   const unsigned char* __restrict__ h1f8,
                                                   const float* __restrict__ b1,
                                                   float* __restrict__ alpha1_out,
                                                   __hip_bfloat16* __restrict__ x1bf) {
    int wv = threadIdx.x >> 6, lane = threadIdx.x & 63;
    int n = blockIdx.x * 4 + wv;
    if (n >= NN) return;
    int start = row_ptr[n], end = row_ptr[n + 1];
    int cnt = end - start;
    int h = lane & 7, j = lane >> 3;
    int hl = lane >> 3;
    unsigned int loff = (unsigned int)(lane << 2);
    float acc0 = 0.f, acc1 = 0.f, acc2 = 0.f, acc3 = 0.f;
    if (cnt > 0 && cnt <= 64) {
        float ad = a_d[(size_t)n * 8 + h];
        if (cnt <= 8)
            gat1_fast<1>(lane, start, cnt, pairs, a_s, ad, h1f8, alpha1_out, acc0, acc1, acc2, acc3);
        else if (cnt <= 16)
            gat1_fast<2>(lane, start, cnt, pairs, a_s, ad, h1f8, alpha1_out, acc0, acc1, acc2, acc3);
        else if (cnt <= 24)
            gat1_fast<3>(lane, start, cnt, pairs, a_s, ad, h1f8, alpha1_out, acc0, acc1, acc2, acc3);
        else if (cnt <= 32)
            gat1_fast<4>(lane, start, cnt, pairs, a_s, ad, h1f8, alpha1_out, acc0, acc1, acc2, acc3);
        else
            gat1_fast<8>(lane, start, cnt, pairs, a_s, ad, h1f8, alpha1_out, acc0, acc1, acc2, acc3);
    } else if (cnt > 64) {
        float ad = a_d[(size_t)n * 8 + h];
        float m = -INFINITY;
        for (int p = start + j; p < end; p += 8) {
            float v = a_s[(size_t)pairs[p].y * 8 + h] + ad;
            v = (v >= 0.f) ? v : NEG_SLOPE * v;
            m = fmaxf(m, v);
        }
        m = fmaxf(m, __shfl_xor(m, 8));
        m = fmaxf(m, __shfl_xor(m, 16));
        m = fmaxf(m, __shfl_xor(m, 32));
        float s = 0.f;
        for (int p = start + j; p < end; p += 8) {
            float v = a_s[(size_t)pairs[p].y * 8 + h] + ad;
            v = (v >= 0.f) ? v : NEG_SLOPE * v;
            s += expf(v - m);
        }
        s += __shfl_xor(s, 8);
        s += __shfl_xor(s, 16);
        s += __shfl_xor(s, 32);
        float inv = 1.f / (s + 1e-16f);
        for (int p = start + j; p < end; p += 8) {
            int2 ep = pairs[p];
            float v = a_s[(size_t)ep.y * 8 + h] + ad;
            v = (v >= 0.f) ? v : NEG_SLOPE * v;
            alpha1_out[(size_t)ep.x * 8 + h] = expf(v - m) * inv;
        }
        float mh = __shfl(m, hl);
        float invh = __shfl(inv, hl);
        float adh = __shfl(ad, hl);
        for (int p = start; p < end; p++) {
            int sp = pairs[p].y;
            float v = a_s[(size_t)sp * 8 + hl] + adh;
            v = (v >= 0.f) ? v : NEG_SLOPE * v;
            float al = expf(v - mh) * invh;
            unsigned int q = *(const unsigned int*)(h1f8 + (((unsigned int)sp << 8) | loff));
            float f0, f1, f2, f3;
            f8x4(q, f0, f1, f2, f3);
            acc0 += al * f0;
            acc1 += al * f1;
            acc2 += al * f2;
            acc3 += al * f3;
        }
    }
    float4 bb = *(const float4*)(b1 + lane * 4);
    float r0 = acc0 + bb.x, r1 = acc1 + bb.y, r2 = acc2 + bb.z, r3 = acc3 + bb.w;
    r0 = (r0 > 0.f) ? r0 : expf(r0) - 1.f;
    r1 = (r1 > 0.f) ? r1 : expf(r1) - 1.f;
    r2 = (r2 > 0.f) ? r2 : expf(r2) - 1.f;
    r3 = (r3 > 0.f) ? r3 : expf(r3) - 1.f;
    ushort4 o;
    o.x = f2bf(r0); o.y = f2bf(r1); o.z = f2bf(r2); o.w = f2bf(r3);
    *(ushort4*)((unsigned short*)x1bf + (size_t)n * HID1 + lane * 4) = o;
}

// ---------------- fused layer-2 softmax + aggregation ----------------

template <int RM>
__device__ __forceinline__ void gat2_fast(int lane, int start, int cnt, int r, int c,
                                          const int2* __restrict__ pairs,
                                          const float* __restrict__ a_s, float ad,
                                          const unsigned char* __restrict__ hf8,
                                          float* __restrict__ alpha2_out,
                                          float& acc0, float& acc1, float& acc2, float& acc3) {
    bool act = lane < cnt;
    int ii = min(lane, cnt - 1);
    int2 ep = pairs[start + ii];
    int sj = ep.y;
    float asv = a_s[sj];
    unsigned int coff = (unsigned int)(c << 2);
    constexpr int NB = RM * 4;
    unsigned int qt[NB];
    #pragma unroll
    for (int t = 0; t < NB; t++) {
        int je = (t >> 2) * 8 + (t & 3) * 2 + r;
        int sje = __shfl(sj, je);
        qt[t] = *(const unsigned int*)(hf8 + (((unsigned int)sje << 7) | coff));
    }
    float v = asv + ad;
    v = (v >= 0.f) ? v : NEG_SLOPE * v;
    float e = act ? v : -INFINITY;
    float m = e;
    #pragma unroll
    for (int off = 1; off < 64; off <<= 1) m = fmaxf(m, __shfl_xor(m, off));
    float ex = expf(e - m);
    float s = ex;
    #pragma unroll
    for (int off = 1; off < 64; off <<= 1) s += __shfl_xor(s, off);
    float al = ex / (s + 1e-16f);
    if (act) alpha2_out[ep.x] = al;
    #pragma unroll
    for (int t = 0; t < NB; t++) {
        int je = (t >> 2) * 8 + (t & 3) * 2 + r;
        float At = __shfl(al, je);
        float f0, f1, f2, f3;
        f8x4(qt[t], f0, f1, f2, f3);
        acc0 += At * f0;
        acc1 += At * f1;
        acc2 += At * f2;
        acc3 += At * f3;
    }
}

__global__ __launch_bounds__(256) void gat2_kernel(const int* __restrict__ row_ptr,
                                                   const int2* __restrict__ pairs,
                                                   const float* __restrict__ a_s,
                                                   const float* __restrict__ a_d,
                                                   const unsigned char* __restrict__ h2f8,
                                                   const float* __restrict__ b2,
                                                   float* __restrict__ alpha2_out,
                                                   __hip_bfloat16* __restrict__ x2bf) {
    int wv = threadIdx.x >> 6, lane = threadIdx.x & 63;
    int n = blockIdx.x * 4 + wv;
    if (n >= NN) return;
    int start = row_ptr[n], end = row_ptr[n + 1];
    int cnt = end - start;
    int r = lane >> 5, c = lane & 31;
    float acc0 = 0.f, acc1 = 0.f, acc2 = 0.f, acc3 = 0.f;
    if (cnt > 0 && cnt <= 64) {
        float ad = a_d[n];
        if (cnt <= 8)
            gat2_fast<1>(lane, start, cnt, r, c, pairs, a_s, ad, h2f8, alpha2_out, acc0, acc1, acc2, acc3);
        else if (cnt <= 16)
            gat2_fast<2>(lane, start, cnt, r, c, pairs, a_s, ad, h2f8, alpha2_out, acc0, acc1, acc2, acc3);
        else if (cnt <= 32)
            gat2_fast<4>(lane, start, cnt, r, c, pairs, a_s, ad, h2f8, alpha2_out, acc0, acc1, acc2, acc3);
        else
            gat2_fast<8>(lane, start, cnt, r, c, pairs, a_s, ad, h2f8, alpha2_out, acc0, acc1, acc2, acc3);
    } else if (cnt > 64) {
        float ad = a_d[n];
        unsigned int coff = (unsigned int)(c << 2);
        float m = -INFINITY;
        for (int p = start + lane; p < end; p += 64) {
            float v = a_s[pairs[p].y] + ad;
            v = (v >= 0.f) ? v : NEG_SLOPE * v;
            m = fmaxf(m, v);
        }
        for (int off = 32; off; off >>= 1) m = fmaxf(m, __shfl_xor(m, off));
        float s = 0.f;
        for (int p = start + lane; p < end; p += 64) {
            float v = a_s[pairs[p].y] + ad;
            v = (v >= 0.f) ? v : NEG_SLOPE * v;
            s += expf(v - m);
        }
        for (int off = 32; off; off >>= 1) s += __shfl_xor(s, off);
        float inv = 1.f / (s + 1e-16f);
        for (int p = start + lane; p < end; p += 64) {
            int2 ep = pairs[p];
            float v = a_s[ep.y] + ad;
            v = (v >= 0.f) ? v : NEG_SLOPE * v;
            alpha2_out[ep.x] = expf(v - m) * inv;
        }
        for (int p = start + r; p < end; p += 2) {
            int sp = pairs[p].y;
            float v = a_s[sp] + ad;
            v = (v >= 0.f) ? v : NEG_SLOPE * v;
            float al = expf(v - m) * inv;
            unsigned int q = *(const unsigned int*)(h2f8 + (((unsigned int)sp << 7) | coff));
            float f0, f1, f2, f3;
            f8x4(q, f0, f1, f2, f3);
            acc0 += al * f0;
            acc1 += al * f1;
            acc2 += al * f2;
            acc3 += al * f3;
        }
    }
    acc0 += __shfl_xor(acc0, 32);
    acc1 += __shfl_xor(acc1, 32);
    acc2 += __shfl_xor(acc2, 32);
    acc3 += __shfl_xor(acc3, 32);
    if (r == 0) {
        float4 bb = *(const float4*)(b2 + c * 4);
        float r0 = acc0 + bb.x, r1 = acc1 + bb.y, r2 = acc2 + bb.z, r3 = acc3 + bb.w;
        r0 = (r0 > 0.f) ? r0 : 0.f;
        r1 = (r1 > 0.f) ? r1 : 0.f;
        r2 = (r2 > 0.f) ? r2 : 0.f;
        r3 = (r3 > 0.f) ? r3 : 0.f;
        ushort4 o;
        o.x = f2bf(r0); o.y = f2bf(r1); o.z = f2bf(r2); o.w = f2bf(r3);
        *(ushort4*)((unsigned short*)x2bf + (size_t)n * HID2 + c * 4) = o;
    }
}

// ---------------- host launch ----------------

extern "C" void kernel_launch(void* const* d_in, const int* in_sizes, int n_in,
                              void* d_out, int out_size, void* d_ws, size_t ws_size,
                              hipStream_t stream) {
    (void)in_sizes; (void)n_in; (void)out_size; (void)ws_size;
    const float* x        = (const float*)d_in[0];
    const int*   eindex   = (const int*)d_in[1];
    const float* W1       = (const float*)d_in[2];
    const float* att_src1 = (const float*)d_in[3];
    const float* att_dst1 = (const float*)d_in[4];
    const float* b1       = (const float*)d_in[5];
    const float* W2       = (const float*)d_in[6];
    const float* att_src2 = (const float*)d_in[7];
    const float* att_dst2 = (const float*)d_in[8];
    const float* b2       = (const float*)d_in[9];
    const float* fcW1     = (const float*)d_in[10];
    const float* fcb1     = (const float*)d_in[11];
    const float* fcW2     = (const float*)d_in[12];
    const float* fcb2     = (const float*)d_in[13];

    const int* src = eindex;
    const int* dst = eindex + EE;

    float* out_n      = (float*)d_out;               // [N]
    float* alpha1_out = out_n + NN;                  // [E,8]
    float* alpha2_out = alpha1_out + (size_t)EE * 8; // [E]

    char* ws = (char*)d_ws;
    size_t off = 0;
    auto alloc = [&](size_t bytes) {
        size_t o = off;
        off = (off + bytes + 255) & ~(size_t)255;
        return o;
    };
    size_t o_rowptr = alloc((NN + 1) * sizeof(int));
    size_t o_cpart  = alloc((size_t)NCH * NN * sizeof(int));
    size_t o_cupart = alloc((size_t)NCH * NN * sizeof(int));
    size_t o_ctot   = alloc(NN * sizeof(int));
    size_t o_excl   = alloc(NN * sizeof(int));
    size_t o_bsum   = alloc(64 * sizeof(int));
    size_t o_pairs  = alloc((size_t)EE * sizeof(int2));
    size_t o_as1    = alloc((size_t)NN * H1 * sizeof(float));
    size_t o_ad1    = alloc((size_t)NN * H1 * sizeof(float));
    size_t o_as2    = alloc((size_t)NN * sizeof(float));
    size_t o_ad2    = alloc((size_t)NN * sizeof(float));
    size_t o_h1f8   = alloc((size_t)NN * HID1);
    size_t o_xbf    = alloc((size_t)NN * IN_DIM * sizeof(__hip_bfloat16));
    size_t o_x1bf   = alloc((size_t)NN * HID1 * sizeof(__hip_bfloat16));
    size_t o_h2f8   = alloc((size_t)NN * HID2);
    size_t o_x2bf   = alloc((size_t)NN * HID2 * sizeof(__hip_bfloat16));
    size_t o_W1p    = alloc((size_t)IN_DIM * HID1 * sizeof(__hip_bfloat16));
    size_t o_W2p    = alloc((size_t)HID1 * HID2 * sizeof(__hip_bfloat16));
    size_t o_fW1p   = alloc((size_t)HID2 * FC1 * sizeof(__hip_bfloat16));

    int*   row_ptr     = (int*)(ws + o_rowptr);
    int*   counts_part = (int*)(ws + o_cpart);
    int*   cursor_part = (int*)(ws + o_cupart);
    int*   counts_tot  = (int*)(ws + o_ctot);
    int*   excl        = (int*)(ws + o_excl);
    int*   bsum        = (int*)(ws + o_bsum);
    int2*  pairs       = (int2*)(ws + o_pairs);
    float* a_s1        = (float*)(ws + o_as1);
    float* a_d1        = (float*)(ws + o_ad1);
    float* a_s2        = (float*)(ws + o_as2);
    float* a_d2        = (float*)(ws + o_ad2);
    unsigned char*  h1f8  = (unsigned char*)(ws + o_h1f8);
    __hip_bfloat16* xbf   = (__hip_bfloat16*)(ws + o_xbf);
    __hip_bfloat16* x1bf  = (__hip_bfloat16*)(ws + o_x1bf);
    unsigned char*  h2f8  = (unsigned char*)(ws + o_h2f8);
    __hip_bfloat16* x2bf  = (__hip_bfloat16*)(ws + o_x2bf);
    __hip_bfloat16* W1p   = (__hip_bfloat16*)(ws + o_W1p);
    __hip_bfloat16* W2p   = (__hip_bfloat16*)(ws + o_W2p);
    __hip_bfloat16* fW1p  = (__hip_bfloat16*)(ws + o_fW1p);

    const int SCAN_NB = (NN + 1023) / 1024;       // 49
    const int NRANGE = (NN + RANGE - 1) / RANGE;  // 49
    const int PREP_N = NN * IN_DIM + IN_DIM * HID1 + HID1 * HID2 + HID2 * FC1;

    hipMemsetAsync(a_s2, 0, NN * sizeof(float), stream);
    hipMemsetAsync(a_d2, 0, NN * sizeof(float), stream);

    // ---- CSR build: 2D-partitioned LDS-atomic histogram + scatter ----
    hist2d_kernel<<<dim3(NRANGE, NCH), 1024, 0, stream>>>(dst, counts_part);
    reduce_kernel<<<(NN + 255) / 256, 256, 0, stream>>>(counts_part, counts_tot);
    scan_a_kernel<<<SCAN_NB, 256, 0, stream>>>(counts_tot, excl, bsum, NN);
    scan_b_kernel<<<1, 64, 0, stream>>>(bsum, row_ptr, SCAN_NB, NN);
    scan_c_kernel<<<SCAN_NB, 256, 0, stream>>>(excl, bsum, row_ptr, NN);
    base2d_kernel<<<(NN + 255) / 256, 256, 0, stream>>>(row_ptr, counts_part, cursor_part);
    scatter2d_kernel<<<dim3(NRANGE, NCH), 1024, 0, stream>>>(src, dst, cursor_part, pairs);

    prep_kernel<<<(PREP_N + 255) / 256, 256, 0, stream>>>(x, xbf, W1, W1p, W2, W2p, fcW1, fW1p);

    mgemm_kernel<1><<<dim3((NN + 127) / 128, HID1 / 64), 256, 0, stream>>>(
        xbf, W1p, h1f8, att_src1, att_dst1, a_s1, a_d1, NN, IN_DIM, HID1);
    gat1_kernel<<<(NN + 3) / 4, 256, 0, stream>>>(row_ptr, pairs, a_s1, a_d1,
                                                  h1f8, b1, alpha1_out, x1bf);

    mgemm_kernel<2><<<dim3((NN + 127) / 128, HID2 / 64), 256, 0, stream>>>(
        x1bf, W2p, h2f8, att_src2, att_dst2, a_s2, a_d2, NN, HID1, HID2);
    gat2_kernel<<<(NN + 3) / 4, 256, 0, stream>>>(row_ptr, pairs, a_s2, a_d2,
                                                  h2f8, b2, alpha2_out, x2bf);

    fc_mfma_kernel<<<(NN + 31) / 32, 256, 0, stream>>>(x2bf, fW1p, fcb1, fcW2, fcb2, out_n);
}

// Round 18
// 217.334 us; speedup vs baseline: 1.8877x; 1.0315x over previous
//
#include <hip/hip_runtime.h>
#include <hip/hip_bf16.h>
#include <hip/hip_fp8.h>
#include <math.h>

#define NN 50000
#define EE 800000
#define IN_DIM 128
#define H1 8
#define D1 32
#define HID1 256
#define HID2 128
#define FC1 512
#define NEG_SLOPE 0.2f
#define RANGE 1024
#define NCH 16
#define CHSZ (EE / NCH)

typedef short v8s __attribute__((ext_vector_type(8)));
typedef float v4f __attribute__((ext_vector_type(4)));
typedef float v2f __attribute__((ext_vector_type(2)));
typedef unsigned int v4u __attribute__((ext_vector_type(4)));

__device__ __forceinline__ float bf2f(unsigned short u) {
    unsigned int x = ((unsigned int)u) << 16;
    return __uint_as_float(x);
}
__device__ __forceinline__ unsigned short f2bf(float v) {
    __hip_bfloat16 h = __float2bfloat16(v);
    return *(unsigned short*)&h;
}
__device__ __forceinline__ unsigned char f2f8(float v) {
    __hip_fp8_e4m3 t(v);
    return (unsigned char)t.__x;
}
__device__ __forceinline__ float f8tof(unsigned char u) {
    __hip_fp8_e4m3 t;
    t.__x = (__hip_fp8_storage_t)u;
    return (float)t;
}

__device__ __forceinline__ void f8x4(unsigned int w, float& f0, float& f1, float& f2, float& f3) {
#if __has_builtin(__builtin_amdgcn_cvt_pk_f32_fp8)
    v2f lo = __builtin_amdgcn_cvt_pk_f32_fp8((int)w, false);
    v2f hi = __builtin_amdgcn_cvt_pk_f32_fp8((int)w, true);
    f0 = lo[0]; f1 = lo[1]; f2 = hi[0]; f3 = hi[1];
#else
    f0 = f8tof((unsigned char)(w & 0xff));
    f1 = f8tof((unsigned char)((w >> 8) & 0xff));
    f2 = f8tof((unsigned char)((w >> 16) & 0xff));
    f3 = f8tof((unsigned char)(w >> 24));
#endif
}

// ---------------- CSR build: 2D (node-range x edge-chunk), LDS atomics only ----------

__global__ __launch_bounds__(1024) void hist2d_kernel(const int* __restrict__ dst,
                                                      int* __restrict__ counts_part) {
    __shared__ int hcnt[RANGE];
    int tid = threadIdx.x;
    int base = blockIdx.x * RANGE;
    int cy = blockIdx.y;
    hcnt[tid] = 0;
    __syncthreads();
    int e_begin = cy * CHSZ;
    int e_end = e_begin + CHSZ;
    for (int e0 = e_begin + tid * 4; e0 < e_end; e0 += 1024 * 4) {
        int4 d4 = *(const int4*)(dst + e0);
        unsigned int a = (unsigned int)(d4.x - base);
        unsigned int b = (unsigned int)(d4.y - base);
        unsigned int c = (unsigned int)(d4.z - base);
        unsigned int d = (unsigned int)(d4.w - base);
        if (a < RANGE) atomicAdd(&hcnt[a], 1);
        if (b < RANGE) atomicAdd(&hcnt[b], 1);
        if (c < RANGE) atomicAdd(&hcnt[c], 1);
        if (d < RANGE) atomicAdd(&hcnt[d], 1);
    }
    __syncthreads();
    int g = base + tid;
    if (g < NN) counts_part[cy * NN + g] = hcnt[tid];
}

// scan over per-node totals, summing the NCH chunk partials inline (reduce fused)
__global__ __launch_bounds__(256) void scan_a_kernel(const int* __restrict__ counts_part,
                                                     int* __restrict__ excl,
                                                     int* __restrict__ bsum, int n) {
    __shared__ int wsum[4];
    int tid = threadIdx.x;
    int base = blockIdx.x * 1024 + tid * 4;
    int v0 = 0, v1 = 0, v2 = 0, v3 = 0;
    if (base + 3 < n) {
        #pragma unroll
        for (int c = 0; c < NCH; c++) {
            int4 t = *(const int4*)(counts_part + (size_t)c * NN + base);
            v0 += t.x; v1 += t.y; v2 += t.z; v3 += t.w;
        }
    } else {
        #pragma unroll
        for (int c = 0; c < NCH; c++) {
            if (base + 0 < n) v0 += counts_part[(size_t)c * NN + base + 0];
            if (base + 1 < n) v1 += counts_part[(size_t)c * NN + base + 1];
            if (base + 2 < n) v2 += counts_part[(size_t)c * NN + base + 2];
            if (base + 3 < n) v3 += counts_part[(size_t)c * NN + base + 3];
        }
    }
    int tot = v0 + v1 + v2 + v3;
    int lane = tid & 63;
    int w = tid >> 6;
    int x = tot;
    #pragma unroll
    for (int off = 1; off < 64; off <<= 1) {
        int y = __shfl_up(x, off);
        if (lane >= off) x += y;
    }
    if (lane == 63) wsum[w] = x;
    __syncthreads();
    int woff = 0;
    for (int i = 0; i < w; i++) woff += wsum[i];
    int et = woff + x - tot;
    if (base + 0 < n) excl[base + 0] = et;
    if (base + 1 < n) excl[base + 1] = et + v0;
    if (base + 2 < n) excl[base + 2] = et + v0 + v1;
    if (base + 3 < n) excl[base + 3] = et + v0 + v1 + v2;
    if (tid == 255) bsum[blockIdx.x] = woff + x;
}

__global__ __launch_bounds__(64) void scan_b_kernel(int* __restrict__ bsum,
                                                    int* __restrict__ row_ptr, int nb, int n) {
    int lane = threadIdx.x;
    int v = (lane < nb) ? bsum[lane] : 0;
    int x = v;
    #pragma unroll
    for (int off = 1; off < 64; off <<= 1) {
        int y = __shfl_up(x, off);
        if (lane >= off) x += y;
    }
    if (lane < nb) bsum[lane] = x - v;
    if (lane == 63) row_ptr[n] = x;
}

__global__ __launch_bounds__(256) void scan_c_kernel(const int* __restrict__ excl,
                                                     const int* __restrict__ bsum,
                                                     int* __restrict__ row_ptr, int n) {
    int base = blockIdx.x * 1024 + threadIdx.x * 4;
    int off = bsum[blockIdx.x];
    #pragma unroll
    for (int j = 0; j < 4; j++) {
        int i = base + j;
        if (i < n) row_ptr[i] = excl[i] + off;
    }
}

// cursor_part[c][d] = row_ptr[d] + sum_{c'<c} counts_part[c'][d]; also zero a_s2/a_d2
__global__ void base2d_kernel(const int* __restrict__ row_ptr, const int* __restrict__ counts_part,
                              int* __restrict__ cursor_part,
                              float* __restrict__ a_s2, float* __restrict__ a_d2) {
    int d = blockIdx.x * blockDim.x + threadIdx.x;
    if (d >= NN) return;
    int running = row_ptr[d];
    #pragma unroll
    for (int c = 0; c < NCH; c++) {
        cursor_part[c * NN + d] = running;
        running += counts_part[c * NN + d];
    }
    a_s2[d] = 0.f;
    a_d2[d] = 0.f;
}

__global__ __launch_bounds__(1024) void scatter2d_kernel(const int* __restrict__ src,
                                                         const int* __restrict__ dst,
                                                         const int* __restrict__ cursor_part,
                                                         int2* __restrict__ pairs) {
    __shared__ int cur[RANGE];
    int tid = threadIdx.x;
    int base = blockIdx.x * RANGE;
    int cy = blockIdx.y;
    int g = base + tid;
    cur[tid] = (g < NN) ? cursor_part[cy * NN + g] : 0;
    __syncthreads();
    int e_begin = cy * CHSZ;
    int e_end = e_begin + CHSZ;
    for (int e0 = e_begin + tid * 4; e0 < e_end; e0 += 1024 * 4) {
        int4 d4 = *(const int4*)(dst + e0);
        int4 s4 = *(const int4*)(src + e0);
        unsigned int a = (unsigned int)(d4.x - base);
        unsigned int b = (unsigned int)(d4.y - base);
        unsigned int c = (unsigned int)(d4.z - base);
        unsigned int d = (unsigned int)(d4.w - base);
        if (a < RANGE) { int p = atomicAdd(&cur[a], 1); pairs[p] = make_int2(e0 + 0, s4.x); }
        if (b < RANGE) { int p = atomicAdd(&cur[b], 1); pairs[p] = make_int2(e0 + 1, s4.y); }
        if (c < RANGE) { int p = atomicAdd(&cur[c], 1); pairs[p] = make_int2(e0 + 2, s4.z); }
        if (d < RANGE) { int p = atomicAdd(&cur[d], 1); pairs[p] = make_int2(e0 + 3, s4.w); }
    }
}

// ---- fused prep ----

__device__ __forceinline__ void pack_one(const float* __restrict__ B,
                                         __hip_bfloat16* __restrict__ Bp,
                                         int K, int N, int idx) {
    int k = idx / N, n = idx % N;
    int ntile = n >> 4, ks = k >> 5, kk = k & 31;
    int lane = (n & 15) | ((kk >> 3) << 4);
    int j = kk & 7;
    int KS = K >> 5;
    Bp[((size_t)(ntile * KS + ks) * 64 + lane) * 8 + j] = __float2bfloat16(B[idx]);
}

__global__ void prep_kernel(const float* __restrict__ x, __hip_bfloat16* __restrict__ xbf,
                            const float* __restrict__ W1, __hip_bfloat16* __restrict__ W1p,
                            const float* __restrict__ W2, __hip_bfloat16* __restrict__ W2p,
                            const float* __restrict__ fcW1, __hip_bfloat16* __restrict__ fW1p) {
    int i = blockIdx.x * blockDim.x + threadIdx.x;
    const int N0 = NN * IN_DIM;
    const int N1 = N0 + IN_DIM * HID1;
    const int N2 = N1 + HID1 * HID2;
    const int N3 = N2 + HID2 * FC1;
    if (i < N0) xbf[i] = __float2bfloat16(x[i]);
    else if (i < N1) pack_one(W1, W1p, IN_DIM, HID1, i - N0);
    else if (i < N2) pack_one(W2, W2p, HID1, HID2, i - N1);
    else if (i < N3) pack_one(fcW1, fW1p, HID2, FC1, i - N2);
}

// ---------------- MFMA GEMM (bf16 in, fp8 out) + fused attention logits ----------------

template <int ATT>
__global__ __launch_bounds__(256) void mgemm_kernel(const __hip_bfloat16* __restrict__ A,
                                                    const __hip_bfloat16* __restrict__ Bp,
                                                    unsigned char* __restrict__ Cf8,
                                                    const float* __restrict__ as_w,
                                                    const float* __restrict__ ad_w,
                                                    float* __restrict__ a_s,
                                                    float* __restrict__ a_d,
                                                    int M, int K, int N) {
    int w = threadIdx.x >> 6, l = threadIdx.x & 63;
    int bm = blockIdx.x * 128 + w * 32;
    int bn = blockIdx.y * 64;
    int lr = l & 15, lk = l >> 4;
    int KS = K >> 5;
    const short* Ab = (const short*)A;
    const short* Bb = (const short*)Bp;
    v4f acc[2][4];
    #pragma unroll
    for (int mi = 0; mi < 2; mi++)
        #pragma unroll
        for (int nt = 0; nt < 4; nt++) acc[mi][nt] = (v4f)(0.f);
    for (int ks = 0; ks < KS; ks++) {
        v8s a[2];
        #pragma unroll
        for (int mi = 0; mi < 2; mi++) {
            int gm = bm + mi * 16 + lr;
            a[mi] = (gm < M) ? *(const v8s*)(Ab + (size_t)gm * K + ks * 32 + lk * 8)
                             : (v8s)(short)0;
        }
        #pragma unroll
        for (int nt = 0; nt < 4; nt++) {
            int ntile = (bn >> 4) + nt;
            v8s b = *(const v8s*)(Bb + ((size_t)(ntile * KS + ks) * 64 + l) * 8);
            acc[0][nt] = __builtin_amdgcn_mfma_f32_16x16x32_bf16(a[0], b, acc[0][nt], 0, 0, 0);
            acc[1][nt] = __builtin_amdgcn_mfma_f32_16x16x32_bf16(a[1], b, acc[1][nt], 0, 0, 0);
        }
    }
    #pragma unroll
    for (int mi = 0; mi < 2; mi++) {
        #pragma unroll
        for (int nt = 0; nt < 4; nt++) {
            int gn = bn + nt * 16 + lr;
            #pragma unroll
            for (int j = 0; j < 4; j++) {
                int gm = bm + mi * 16 + lk * 4 + j;
                if (gm < M)
                    Cf8[(size_t)gm * N + gn] = f2f8(acc[mi][nt][j]);
            }
        }
    }
    float ws0 = as_w[bn + lr], ws1 = as_w[bn + 16 + lr];
    float ws2 = as_w[bn + 32 + lr], ws3 = as_w[bn + 48 + lr];
    float wd0 = ad_w[bn + lr], wd1 = ad_w[bn + 16 + lr];
    float wd2 = ad_w[bn + 32 + lr], wd3 = ad_w[bn + 48 + lr];
    float sA[2][4], dA[2][4], sB[2][4], dB[2][4];
    #pragma unroll
    for (int mi = 0; mi < 2; mi++)
        #pragma unroll
        for (int j = 0; j < 4; j++) {
            if constexpr (ATT == 1) {
                sA[mi][j] = acc[mi][0][j] * ws0 + acc[mi][1][j] * ws1;
                sB[mi][j] = acc[mi][2][j] * ws2 + acc[mi][3][j] * ws3;
                dA[mi][j] = acc[mi][0][j] * wd0 + acc[mi][1][j] * wd1;
                dB[mi][j] = acc[mi][2][j] * wd2 + acc[mi][3][j] * wd3;
            } else {
                sA[mi][j] = acc[mi][0][j] * ws0 + acc[mi][1][j] * ws1
                          + acc[mi][2][j] * ws2 + acc[mi][3][j] * ws3;
                dA[mi][j] = acc[mi][0][j] * wd0 + acc[mi][1][j] * wd1
                          + acc[mi][2][j] * wd2 + acc[mi][3][j] * wd3;
                sB[mi][j] = 0.f; dB[mi][j] = 0.f;
            }
        }
    #pragma unroll
    for (int off = 1; off < 16; off <<= 1) {
        #pragma unroll
        for (int mi = 0; mi < 2; mi++)
            #pragma unroll
            for (int j = 0; j < 4; j++) {
                sA[mi][j] += __shfl_xor(sA[mi][j], off);
                dA[mi][j] += __shfl_xor(dA[mi][j], off);
                if constexpr (ATT == 1) {
                    sB[mi][j] += __shfl_xor(sB[mi][j], off);
                    dB[mi][j] += __shfl_xor(dB[mi][j], off);
                }
            }
    }
    if (lr == 0) {
        #pragma unroll
        for (int mi = 0; mi < 2; mi++)
            #pragma unroll
            for (int j = 0; j < 4; j++) {
                int row = bm + mi * 16 + lk * 4 + j;
                if (row < M) {
                    if constexpr (ATT == 1) {
                        int h0 = bn >> 5;
                        a_s[(size_t)row * 8 + h0]     = sA[mi][j];
                        a_s[(size_t)row * 8 + h0 + 1] = sB[mi][j];
                        a_d[(size_t)row * 8 + h0]     = dA[mi][j];
                        a_d[(size_t)row * 8 + h0 + 1] = dB[mi][j];
                    } else {
                        atomicAdd(&a_s[row], sA[mi][j]);
                        atomicAdd(&a_d[row], dA[mi][j]);
                    }
                }
            }
    }
}

// ---------------- fused FC head via MFMA ----------------

__global__ __launch_bounds__(256) void fc_mfma_kernel(const __hip_bfloat16* __restrict__ A,
                                                      const __hip_bfloat16* __restrict__ Bp,
                                                      const float* __restrict__ fcb1,
                                                      const float* __restrict__ fcW2,
                                                      const float* __restrict__ fcb2,
                                                      float* __restrict__ out) {
    __shared__ float red[4][32];
    int w = threadIdx.x >> 6, l = threadIdx.x & 63;
    int bm = blockIdx.x * 32;
    int lr = l & 15, lk = l >> 4;
    const int K = HID2, KS = K >> 5;
    const short* Ab = (const short*)A;
    const short* Bb = (const short*)Bp;
    v4f acc[2][8];
    #pragma unroll
    for (int mi = 0; mi < 2; mi++)
        #pragma unroll
        for (int nt = 0; nt < 8; nt++) acc[mi][nt] = (v4f)(0.f);
    for (int ks = 0; ks < KS; ks++) {
        v8s a[2];
        #pragma unroll
        for (int mi = 0; mi < 2; mi++) {
            int gm = bm + mi * 16 + lr;
            a[mi] = (gm < NN) ? *(const v8s*)(Ab + (size_t)gm * K + ks * 32 + lk * 8)
                              : (v8s)(short)0;
        }
        #pragma unroll
        for (int nt = 0; nt < 8; nt++) {
            int ntile = w * 8 + nt;
            v8s b = *(const v8s*)(Bb + ((size_t)(ntile * KS + ks) * 64 + l) * 8);
            acc[0][nt] = __builtin_amdgcn_mfma_f32_16x16x32_bf16(a[0], b, acc[0][nt], 0, 0, 0);
            acc[1][nt] = __builtin_amdgcn_mfma_f32_16x16x32_bf16(a[1], b, acc[1][nt], 0, 0, 0);
        }
    }
    float p[2][4];
    #pragma unroll
    for (int mi = 0; mi < 2; mi++)
        #pragma unroll
        for (int j = 0; j < 4; j++) p[mi][j] = 0.f;
    #pragma unroll
    for (int nt = 0; nt < 8; nt++) {
        int col = w * 128 + nt * 16 + lr;
        float b1v = fcb1[col], w2v = fcW2[col];
        #pragma unroll
        for (int mi = 0; mi < 2; mi++) {
            #pragma unroll
            for (int j = 0; j < 4; j++) {
                float v = acc[mi][nt][j] + b1v;
                p[mi][j] += ((v > 0.f) ? v : 0.f) * w2v;
            }
        }
    }
    #pragma unroll
    for (int mi = 0; mi < 2; mi++)
        #pragma unroll
        for (int j = 0; j < 4; j++) {
            float v = p[mi][j];
            v += __shfl_xor(v, 1);
            v += __shfl_xor(v, 2);
            v += __shfl_xor(v, 4);
            v += __shfl_xor(v, 8);
            p[mi][j] = v;
        }
    if (lr == 0) {
        #pragma unroll
        for (int mi = 0; mi < 2; mi++)
            #pragma unroll
            for (int j = 0; j < 4; j++) red[w][mi * 16 + lk * 4 + j] = p[mi][j];
    }
    __syncthreads();
    int tid = threadIdx.x;
    if (tid < 32) {
        int gm = bm + tid;
        if (gm < NN)
            out[gm] = red[0][tid] + red[1][tid] + red[2][tid] + red[3][tid] + fcb2[0];
    }
}

// ---------------- fused layer-1 softmax + aggregation ----------------

template <int KM>
__device__ __forceinline__ void gat1_fast(int lane, int start, int cnt,
                                          const int2* __restrict__ pairs,
                                          const float* __restrict__ a_s, float ad,
                                          const unsigned char* __restrict__ hf8,
                                          float* __restrict__ alpha1_out,
                                          float& acc0, float& acc1, float& acc2, float& acc3) {
    int h = lane & 7, j = lane >> 3;
    int hl = lane >> 3;
    int cl = min(lane, cnt - 1);
    int2 ep = pairs[start + cl];
    int e_all = ep.x, s_all = ep.y;
    unsigned int loff = (unsigned int)(lane << 2);

    if constexpr (KM <= 4) {
        constexpr int NB = KM * 8;
        int sj[KM];
        float ev[KM];
        #pragma unroll
        for (int k = 0; k < KM; k++) {
            int idx = j + k * 8;
            sj[k] = __shfl(s_all, idx);
            ev[k] = a_s[(size_t)sj[k] * 8 + h];
        }
        unsigned int qt[NB];
        #pragma unroll
        for (int e = 0; e < NB; e++) {
            int sje = __shfl(s_all, e);
            qt[e] = *(const unsigned int*)(hf8 + (((unsigned int)sje << 8) | loff));
        }
        float ex[KM];
        #pragma unroll
        for (int k = 0; k < KM; k++) {
            int idx = j + k * 8;
            float v = ev[k] + ad;
            v = (v >= 0.f) ? v : NEG_SLOPE * v;
            ex[k] = (idx < cnt) ? v : -INFINITY;
        }
        float m = ex[0];
        #pragma unroll
        for (int k = 1; k < KM; k++) m = fmaxf(m, ex[k]);
        m = fmaxf(m, __shfl_xor(m, 8));
        m = fmaxf(m, __shfl_xor(m, 16));
        m = fmaxf(m, __shfl_xor(m, 32));
        float s = 0.f;
        #pragma unroll
        for (int k = 0; k < KM; k++) {
            ex[k] = expf(ex[k] - m);
            s += ex[k];
        }
        s += __shfl_xor(s, 8);
        s += __shfl_xor(s, 16);
        s += __shfl_xor(s, 32);
        float inv = 1.f / (s + 1e-16f);
        #pragma unroll
        for (int k = 0; k < KM; k++) ex[k] *= inv;
        #pragma unroll
        for (int k = 0; k < KM; k++) {
            int idx = j + k * 8;
            int eo = __shfl(e_all, idx);
            if (idx < cnt) alpha1_out[(size_t)eo * 8 + h] = ex[k];
        }
        #pragma unroll
        for (int e = 0; e < NB; e++) {
            float At = __shfl(ex[e >> 3], (e & 7) * 8 + hl);
            float f0, f1, f2, f3;
            f8x4(qt[e], f0, f1, f2, f3);
            acc0 += At * f0;
            acc1 += At * f1;
            acc2 += At * f2;
            acc3 += At * f3;
        }
    } else {
        float ex[KM];
        int sj[KM];
        #pragma unroll
        for (int k = 0; k < KM; k++) {
            int idx = j + k * 8;
            sj[k] = __shfl(s_all, idx);
            float v = a_s[(size_t)sj[k] * 8 + h] + ad;
            v = (v >= 0.f) ? v : NEG_SLOPE * v;
            ex[k] = (idx < cnt) ? v : -INFINITY;
        }
        float m = ex[0];
        #pragma unroll
        for (int k = 1; k < KM; k++) m = fmaxf(m, ex[k]);
        m = fmaxf(m, __shfl_xor(m, 8));
        m = fmaxf(m, __shfl_xor(m, 16));
        m = fmaxf(m, __shfl_xor(m, 32));
        float s = 0.f;
        #pragma unroll
        for (int k = 0; k < KM; k++) {
            ex[k] = expf(ex[k] - m);
            s += ex[k];
        }
        s += __shfl_xor(s, 8);
        s += __shfl_xor(s, 16);
        s += __shfl_xor(s, 32);
        float inv = 1.f / (s + 1e-16f);
        #pragma unroll
        for (int k = 0; k < KM; k++) ex[k] *= inv;
        #pragma unroll
        for (int k = 0; k < KM; k++) {
            int idx = j + k * 8;
            int eo = __shfl(e_all, idx);
            if (idx < cnt) alpha1_out[(size_t)eo * 8 + h] = ex[k];
        }
        unsigned int pk[KM];
        #pragma unroll
        for (int k = 0; k < KM; k++)
            pk[k] = ((unsigned int)sj[k] << 16) | (unsigned int)f2bf(ex[k]);
        int rounds = (cnt + 7) >> 3;
        #pragma unroll
        for (int K = 0; K < KM; K++) {
            if (K < rounds) {
                float At[8];
                unsigned int qt[8];
                #pragma unroll
                for (int t = 0; t < 8; t++) {
                    unsigned int wv = (unsigned int)__shfl((int)pk[K], t * 8 + hl);
                    At[t] = bf2f((unsigned short)wv);
                    qt[t] = *(const unsigned int*)(hf8 + (((wv >> 16) << 8) | loff));
                }
                #pragma unroll
                for (int t = 0; t < 8; t++) {
                    float f0, f1, f2, f3;
                    f8x4(qt[t], f0, f1, f2, f3);
                    acc0 += At[t] * f0;
                    acc1 += At[t] * f1;
                    acc2 += At[t] * f2;
                    acc3 += At[t] * f3;
                }
            }
        }
    }
}

__global__ __launch_bounds__(512) void gat1_kernel(const int* __restrict__ row_ptr,
                                                   const int2* __restrict__ pairs,
                                                   const float* __restrict__ a_s,
                                                   const float* __restrict__ a_d,
                                                   const unsigned char* __restrict__ h1f8,
                                                   const float* __restrict__ b1,
                                                   float* __restrict__ alpha1_out,
                                                   __hip_bfloat16* __restrict__ x1bf) {
    int wv = threadIdx.x >> 6, lane = threadIdx.x & 63;
    int n = blockIdx.x * 8 + wv;
    if (n >= NN) return;
    int start = row_ptr[n], end = row_ptr[n + 1];
    int cnt = end - start;
    int h = lane & 7, j = lane >> 3;
    int hl = lane >> 3;
    unsigned int loff = (unsigned int)(lane << 2);
    float acc0 = 0.f, acc1 = 0.f, acc2 = 0.f, acc3 = 0.f;
    if (cnt > 0 && cnt <= 64) {
        float ad = a_d[(size_t)n * 8 + h];
        if (cnt <= 8)
            gat1_fast<1>(lane, start, cnt, pairs, a_s, ad, h1f8, alpha1_out, acc0, acc1, acc2, acc3);
        else if (cnt <= 16)
            gat1_fast<2>(lane, start, cnt, pairs, a_s, ad, h1f8, alpha1_out, acc0, acc1, acc2, acc3);
        else if (cnt <= 24)
            gat1_fast<3>(lane, start, cnt, pairs, a_s, ad, h1f8, alpha1_out, acc0, acc1, acc2, acc3);
        else if (cnt <= 32)
            gat1_fast<4>(lane, start, cnt, pairs, a_s, ad, h1f8, alpha1_out, acc0, acc1, acc2, acc3);
        else
            gat1_fast<8>(lane, start, cnt, pairs, a_s, ad, h1f8, alpha1_out, acc0, acc1, acc2, acc3);
    } else if (cnt > 64) {
        float ad = a_d[(size_t)n * 8 + h];
        float m = -INFINITY;
        for (int p = start + j; p < end; p += 8) {
            float v = a_s[(size_t)pairs[p].y * 8 + h] + ad;
            v = (v >= 0.f) ? v : NEG_SLOPE * v;
            m = fmaxf(m, v);
        }
        m = fmaxf(m, __shfl_xor(m, 8));
        m = fmaxf(m, __shfl_xor(m, 16));
        m = fmaxf(m, __shfl_xor(m, 32));
        float s = 0.f;
        for (int p = start + j; p < end; p += 8) {
            float v = a_s[(size_t)pairs[p].y * 8 + h] + ad;
            v = (v >= 0.f) ? v : NEG_SLOPE * v;
            s += expf(v - m);
        }
        s += __shfl_xor(s, 8);
        s += __shfl_xor(s, 16);
        s += __shfl_xor(s, 32);
        float inv = 1.f / (s + 1e-16f);
        for (int p = start + j; p < end; p += 8) {
            int2 ep = pairs[p];
            float v = a_s[(size_t)ep.y * 8 + h] + ad;
            v = (v >= 0.f) ? v : NEG_SLOPE * v;
            alpha1_out[(size_t)ep.x * 8 + h] = expf(v - m) * inv;
        }
        float mh = __shfl(m, hl);
        float invh = __shfl(inv, hl);
        float adh = __shfl(ad, hl);
        for (int p = start; p < end; p++) {
            int sp = pairs[p].y;
            float v = a_s[(size_t)sp * 8 + hl] + adh;
            v = (v >= 0.f) ? v : NEG_SLOPE * v;
            float al = expf(v - mh) * invh;
            unsigned int q = *(const unsigned int*)(h1f8 + (((unsigned int)sp << 8) | loff));
            float f0, f1, f2, f3;
            f8x4(q, f0, f1, f2, f3);
            acc0 += al * f0;
            acc1 += al * f1;
            acc2 += al * f2;
            acc3 += al * f3;
        }
    }
    float4 bb = *(const float4*)(b1 + lane * 4);
    float r0 = acc0 + bb.x, r1 = acc1 + bb.y, r2 = acc2 + bb.z, r3 = acc3 + bb.w;
    r0 = (r0 > 0.f) ? r0 : expf(r0) - 1.f;
    r1 = (r1 > 0.f) ? r1 : expf(r1) - 1.f;
    r2 = (r2 > 0.f) ? r2 : expf(r2) - 1.f;
    r3 = (r3 > 0.f) ? r3 : expf(r3) - 1.f;
    ushort4 o;
    o.x = f2bf(r0); o.y = f2bf(r1); o.z = f2bf(r2); o.w = f2bf(r3);
    *(ushort4*)((unsigned short*)x1bf + (size_t)n * HID1 + lane * 4) = o;
}

// ---------------- fused layer-2 softmax + aggregation ----------------

template <int RM>
__device__ __forceinline__ void gat2_fast(int lane, int start, int cnt, int r, int c,
                                          const int2* __restrict__ pairs,
                                          const float* __restrict__ a_s, float ad,
                                          const unsigned char* __restrict__ hf8,
                                          float* __restrict__ alpha2_out,
                                          float& acc0, float& acc1, float& acc2, float& acc3) {
    bool act = lane < cnt;
    int ii = min(lane, cnt - 1);
    int2 ep = pairs[start + ii];
    int sj = ep.y;
    float asv = a_s[sj];
    unsigned int coff = (unsigned int)(c << 2);
    constexpr int NB = RM * 4;
    unsigned int qt[NB];
    #pragma unroll
    for (int t = 0; t < NB; t++) {
        int je = (t >> 2) * 8 + (t & 3) * 2 + r;
        int sje = __shfl(sj, je);
        qt[t] = *(const unsigned int*)(hf8 + (((unsigned int)sje << 7) | coff));
    }
    float v = asv + ad;
    v = (v >= 0.f) ? v : NEG_SLOPE * v;
    float e = act ? v : -INFINITY;
    float m = e;
    #pragma unroll
    for (int off = 1; off < 64; off <<= 1) m = fmaxf(m, __shfl_xor(m, off));
    float ex = expf(e - m);
    float s = ex;
    #pragma unroll
    for (int off = 1; off < 64; off <<= 1) s += __shfl_xor(s, off);
    float al = ex / (s + 1e-16f);
    if (act) alpha2_out[ep.x] = al;
    #pragma unroll
    for (int t = 0; t < NB; t++) {
        int je = (t >> 2) * 8 + (t & 3) * 2 + r;
        float At = __shfl(al, je);
        float f0, f1, f2, f3;
        f8x4(qt[t], f0, f1, f2, f3);
        acc0 += At * f0;
        acc1 += At * f1;
        acc2 += At * f2;
        acc3 += At * f3;
    }
}

__global__ __launch_bounds__(256) void gat2_kernel(const int* __restrict__ row_ptr,
                                                   const int2* __restrict__ pairs,
                                                   const float* __restrict__ a_s,
                                                   const float* __restrict__ a_d,
                                                   const unsigned char* __restrict__ h2f8,
                                                   const float* __restrict__ b2,
                                                   float* __restrict__ alpha2_out,
                                                   __hip_bfloat16* __restrict__ x2bf) {
    int wv = threadIdx.x >> 6, lane = threadIdx.x & 63;
    int n = blockIdx.x * 4 + wv;
    if (n >= NN) return;
    int start = row_ptr[n], end = row_ptr[n + 1];
    int cnt = end - start;
    int r = lane >> 5, c = lane & 31;
    float acc0 = 0.f, acc1 = 0.f, acc2 = 0.f, acc3 = 0.f;
    if (cnt > 0 && cnt <= 64) {
        float ad = a_d[n];
        if (cnt <= 8)
            gat2_fast<1>(lane, start, cnt, r, c, pairs, a_s, ad, h2f8, alpha2_out, acc0, acc1, acc2, acc3);
        else if (cnt <= 16)
            gat2_fast<2>(lane, start, cnt, r, c, pairs, a_s, ad, h2f8, alpha2_out, acc0, acc1, acc2, acc3);
        else if (cnt <= 32)
            gat2_fast<4>(lane, start, cnt, r, c, pairs, a_s, ad, h2f8, alpha2_out, acc0, acc1, acc2, acc3);
        else
            gat2_fast<8>(lane, start, cnt, r, c, pairs, a_s, ad, h2f8, alpha2_out, acc0, acc1, acc2, acc3);
    } else if (cnt > 64) {
        float ad = a_d[n];
        unsigned int coff = (unsigned int)(c << 2);
        float m = -INFINITY;
        for (int p = start + lane; p < end; p += 64) {
            float v = a_s[pairs[p].y] + ad;
            v = (v >= 0.f) ? v : NEG_SLOPE * v;
            m = fmaxf(m, v);
        }
        for (int off = 32; off; off >>= 1) m = fmaxf(m, __shfl_xor(m, off));
        float s = 0.f;
        for (int p = start + lane; p < end; p += 64) {
            float v = a_s[pairs[p].y] + ad;
            v = (v >= 0.f) ? v : NEG_SLOPE * v;
            s += expf(v - m);
        }
        for (int off = 32; off; off >>= 1) s += __shfl_xor(s, off);
        float inv = 1.f / (s + 1e-16f);
        for (int p = start + lane; p < end; p += 64) {
            int2 ep = pairs[p];
            float v = a_s[ep.y] + ad;
            v = (v >= 0.f) ? v : NEG_SLOPE * v;
            alpha2_out[ep.x] = expf(v - m) * inv;
        }
        for (int p = start + r; p < end; p += 2) {
            int sp = pairs[p].y;
            float v = a_s[sp] + ad;
            v = (v >= 0.f) ? v : NEG_SLOPE * v;
            float al = expf(v - m) * inv;
            unsigned int q = *(const unsigned int*)(h2f8 + (((unsigned int)sp << 7) | coff));
            float f0, f1, f2, f3;
            f8x4(q, f0, f1, f2, f3);
            acc0 += al * f0;
            acc1 += al * f1;
            acc2 += al * f2;
            acc3 += al * f3;
        }
    }
    acc0 += __shfl_xor(acc0, 32);
    acc1 += __shfl_xor(acc1, 32);
    acc2 += __shfl_xor(acc2, 32);
    acc3 += __shfl_xor(acc3, 32);
    if (r == 0) {
        float4 bb = *(const float4*)(b2 + c * 4);
        float r0 = acc0 + bb.x, r1 = acc1 + bb.y, r2 = acc2 + bb.z, r3 = acc3 + bb.w;
        r0 = (r0 > 0.f) ? r0 : 0.f;
        r1 = (r1 > 0.f) ? r1 : 0.f;
        r2 = (r2 > 0.f) ? r2 : 0.f;
        r3 = (r3 > 0.f) ? r3 : 0.f;
        ushort4 o;
        o.x = f2bf(r0); o.y = f2bf(r1); o.z = f2bf(r2); o.w = f2bf(r3);
        *(ushort4*)((unsigned short*)x2bf + (size_t)n * HID2 + c * 4) = o;
    }
}

// ---------------- host launch ----------------

extern "C" void kernel_launch(void* const* d_in, const int* in_sizes, int n_in,
                              void* d_out, int out_size, void* d_ws, size_t ws_size,
                              hipStream_t stream) {
    (void)in_sizes; (void)n_in; (void)out_size; (void)ws_size;
    const float* x        = (const float*)d_in[0];
    const int*   eindex   = (const int*)d_in[1];
    const float* W1       = (const float*)d_in[2];
    const float* att_src1 = (const float*)d_in[3];
    const float* att_dst1 = (const float*)d_in[4];
    const float* b1       = (const float*)d_in[5];
    const float* W2       = (const float*)d_in[6];
    const float* att_src2 = (const float*)d_in[7];
    const float* att_dst2 = (const float*)d_in[8];
    const float* b2       = (const float*)d_in[9];
    const float* fcW1     = (const float*)d_in[10];
    const float* fcb1     = (const float*)d_in[11];
    const float* fcW2     = (const float*)d_in[12];
    const float* fcb2     = (const float*)d_in[13];

    const int* src = eindex;
    const int* dst = eindex + EE;

    float* out_n      = (float*)d_out;               // [N]
    float* alpha1_out = out_n + NN;                  // [E,8]
    float* alpha2_out = alpha1_out + (size_t)EE * 8; // [E]

    char* ws = (char*)d_ws;
    size_t off = 0;
    auto alloc = [&](size_t bytes) {
        size_t o = off;
        off = (off + bytes + 255) & ~(size_t)255;
        return o;
    };
    size_t o_rowptr = alloc((NN + 1) * sizeof(int));
    size_t o_cpart  = alloc((size_t)NCH * NN * sizeof(int));
    size_t o_cupart = alloc((size_t)NCH * NN * sizeof(int));
    size_t o_excl   = alloc(NN * sizeof(int));
    size_t o_bsum   = alloc(64 * sizeof(int));
    size_t o_pairs  = alloc((size_t)EE * sizeof(int2));
    size_t o_as1    = alloc((size_t)NN * H1 * sizeof(float));
    size_t o_ad1    = alloc((size_t)NN * H1 * sizeof(float));
    size_t o_as2    = alloc((size_t)NN * sizeof(float));
    size_t o_ad2    = alloc((size_t)NN * sizeof(float));
    size_t o_h1f8   = alloc((size_t)NN * HID1);
    size_t o_xbf    = alloc((size_t)NN * IN_DIM * sizeof(__hip_bfloat16));
    size_t o_x1bf   = alloc((size_t)NN * HID1 * sizeof(__hip_bfloat16));
    size_t o_h2f8   = alloc((size_t)NN * HID2);
    size_t o_x2bf   = alloc((size_t)NN * HID2 * sizeof(__hip_bfloat16));
    size_t o_W1p    = alloc((size_t)IN_DIM * HID1 * sizeof(__hip_bfloat16));
    size_t o_W2p    = alloc((size_t)HID1 * HID2 * sizeof(__hip_bfloat16));
    size_t o_fW1p   = alloc((size_t)HID2 * FC1 * sizeof(__hip_bfloat16));

    int*   row_ptr     = (int*)(ws + o_rowptr);
    int*   counts_part = (int*)(ws + o_cpart);
    int*   cursor_part = (int*)(ws + o_cupart);
    int*   excl        = (int*)(ws + o_excl);
    int*   bsum        = (int*)(ws + o_bsum);
    int2*  pairs       = (int2*)(ws + o_pairs);
    float* a_s1        = (float*)(ws + o_as1);
    float* a_d1        = (float*)(ws + o_ad1);
    float* a_s2        = (float*)(ws + o_as2);
    float* a_d2        = (float*)(ws + o_ad2);
    unsigned char*  h1f8  = (unsigned char*)(ws + o_h1f8);
    __hip_bfloat16* xbf   = (__hip_bfloat16*)(ws + o_xbf);
    __hip_bfloat16* x1bf  = (__hip_bfloat16*)(ws + o_x1bf);
    unsigned char*  h2f8  = (unsigned char*)(ws + o_h2f8);
    __hip_bfloat16* x2bf  = (__hip_bfloat16*)(ws + o_x2bf);
    __hip_bfloat16* W1p   = (__hip_bfloat16*)(ws + o_W1p);
    __hip_bfloat16* W2p   = (__hip_bfloat16*)(ws + o_W2p);
    __hip_bfloat16* fW1p  = (__hip_bfloat16*)(ws + o_fW1p);

    const int SCAN_NB = (NN + 1023) / 1024;       // 49
    const int NRANGE = (NN + RANGE - 1) / RANGE;  // 49
    const int PREP_N = NN * IN_DIM + IN_DIM * HID1 + HID1 * HID2 + HID2 * FC1;

    // ---- CSR build: 2D-partitioned LDS-atomic histogram + scatter ----
    hist2d_kernel<<<dim3(NRANGE, NCH), 1024, 0, stream>>>(dst, counts_part);
    scan_a_kernel<<<SCAN_NB, 256, 0, stream>>>(counts_part, excl, bsum, NN);
    scan_b_kernel<<<1, 64, 0, stream>>>(bsum, row_ptr, SCAN_NB, NN);
    scan_c_kernel<<<SCAN_NB, 256, 0, stream>>>(excl, bsum, row_ptr, NN);
    base2d_kernel<<<(NN + 255) / 256, 256, 0, stream>>>(row_ptr, counts_part, cursor_part,
                                                        a_s2, a_d2);
    scatter2d_kernel<<<dim3(NRANGE, NCH), 1024, 0, stream>>>(src, dst, cursor_part, pairs);

    prep_kernel<<<(PREP_N + 255) / 256, 256, 0, stream>>>(x, xbf, W1, W1p, W2, W2p, fcW1, fW1p);

    mgemm_kernel<1><<<dim3((NN + 127) / 128, HID1 / 64), 256, 0, stream>>>(
        xbf, W1p, h1f8, att_src1, att_dst1, a_s1, a_d1, NN, IN_DIM, HID1);
    gat1_kernel<<<(NN + 7) / 8, 512, 0, stream>>>(row_ptr, pairs, a_s1, a_d1,
                                                  h1f8, b1, alpha1_out, x1bf);

    mgemm_kernel<2><<<dim3((NN + 127) / 128, HID2 / 64), 256, 0, stream>>>(
        x1bf, W2p, h2f8, att_src2, att_dst2, a_s2, a_d2, NN, HID1, HID2);
    gat2_kernel<<<(NN + 3) / 4, 256, 0, stream>>>(row_ptr, pairs, a_s2, a_d2,
                                                  h2f8, b2, alpha2_out, x2bf);

    fc_mfma_kernel<<<(NN + 31) / 32, 256, 0, stream>>>(x2bf, fW1p, fcb1, fcW2, fcb2, out_n);
}